// Round 1
// baseline (291.406 us; speedup 1.0000x reference)
//
#include <hip/hip_runtime.h>
#include <hip/hip_bf16.h>

#define DMODEL 1024
#define NHEAD  16
#define DHEAD  64
#define BB     4
#define MM     1024
#define NN     2048

typedef __attribute__((ext_vector_type(8))) short bf16x8;
typedef __attribute__((ext_vector_type(4))) float f32x4;

__device__ __forceinline__ unsigned short f2bf(float f) {
  unsigned int u = __builtin_bit_cast(unsigned int, f);
  unsigned int r = (u + 0x7fffu + ((u >> 16) & 1u)) >> 16;
  return (unsigned short)r;
}

// ---------------------------------------------------------------- cast f32 -> bf16
__global__ __launch_bounds__(256)
void cast_kernel(const float* __restrict__ src, unsigned short* __restrict__ dst, int n4) {
  int i = blockIdx.x * 256 + threadIdx.x;
  if (i >= n4) return;
  const float4 v = ((const float4*)src)[i];
  union { unsigned short us[4]; unsigned long long u64; } o;
  o.us[0] = f2bf(v.x); o.us[1] = f2bf(v.y); o.us[2] = f2bf(v.z); o.us[3] = f2bf(v.w);
  *(unsigned long long*)(dst + (size_t)i * 4) = o.u64;
}

// ---------------------------------------------------------------- GEMM  C = A @ W^T (+bias)
// A: (rows x 1024) bf16 row-major.  W: (1024 x 1024) bf16 row-major (torch Linear weight).
// MODE 0: Cbf = bf16(acc + bias)
// MODE 1: Cbf = bf16((acc + bias) * 0.125)        (pre-scaled q)
// MODE 2: Cf32 = resid + acc + bias               (fp32 x for LayerNorm)
template<int MODE>
__global__ __launch_bounds__(256)
void gemm_bt(const unsigned short* __restrict__ A,
             const unsigned short* __restrict__ W,
             const float* __restrict__ bias,
             const float* __restrict__ resid,
             unsigned short* __restrict__ Cbf,
             float* __restrict__ Cf32)
{
  __shared__ unsigned short As[2][128 * 32];
  __shared__ unsigned short Ws[2][128 * 32];

  const int tid  = threadIdx.x;
  const int wave = tid >> 6;
  const int lane = tid & 63;
  const int l15  = lane & 15;
  const int l4   = lane >> 4;
  const int wm   = wave >> 1;
  const int wn   = wave & 1;
  const size_t row0 = (size_t)blockIdx.x * 128;
  const size_t col0 = (size_t)blockIdx.y * 128;

  f32x4 acc[4][4] = {};

  auto stage = [&](int buf, int kt) {
    const unsigned short* Ab = A + row0 * DMODEL + kt * 32;
    const unsigned short* Wb = W + col0 * DMODEL + kt * 32;
#pragma unroll
    for (int is = 0; is < 2; ++is) {
      int cc  = (wave * 2 + is) * 64 + lane;   // 0..511 : 16B chunk id
      int r   = cc >> 2;                        // tile row 0..127
      int ch  = cc & 3;                         // physical 16B chunk in row
      int sch = ch ^ (r & 3);                   // pre-swizzled source chunk
      __builtin_amdgcn_global_load_lds(
          (const __attribute__((address_space(1))) void*)(Ab + (size_t)r * DMODEL + sch * 8),
          (__attribute__((address_space(3))) void*)(&As[buf][cc * 8]), 16, 0, 0);
      __builtin_amdgcn_global_load_lds(
          (const __attribute__((address_space(1))) void*)(Wb + (size_t)r * DMODEL + sch * 8),
          (__attribute__((address_space(3))) void*)(&Ws[buf][cc * 8]), 16, 0, 0);
    }
  };

  stage(0, 0);
  __syncthreads();

  for (int kt = 0; kt < 32; ++kt) {
    const int cur = kt & 1;
    if (kt < 31) stage(cur ^ 1, kt + 1);

    bf16x8 af[4], bfr[4];
#pragma unroll
    for (int mi = 0; mi < 4; ++mi) {
      int r = wm * 64 + mi * 16 + l15;
      af[mi] = *(const bf16x8*)&As[cur][r * 32 + ((l4 ^ (r & 3)) << 3)];
    }
#pragma unroll
    for (int ni = 0; ni < 4; ++ni) {
      int r = wn * 64 + ni * 16 + l15;
      bfr[ni] = *(const bf16x8*)&Ws[cur][r * 32 + ((l4 ^ (r & 3)) << 3)];
    }
#pragma unroll
    for (int mi = 0; mi < 4; ++mi)
#pragma unroll
      for (int ni = 0; ni < 4; ++ni)
        acc[mi][ni] = __builtin_amdgcn_mfma_f32_16x16x32_bf16(af[mi], bfr[ni], acc[mi][ni], 0, 0, 0);

    __syncthreads();
  }

  // epilogue: C/D layout col=lane&15, row=(lane>>4)*4+i  [m89-verified]
#pragma unroll
  for (int mi = 0; mi < 4; ++mi) {
#pragma unroll
    for (int ni = 0; ni < 4; ++ni) {
      const int col = (int)col0 + wn * 64 + ni * 16 + l15;
      const float bcol = bias[col];
#pragma unroll
      for (int i = 0; i < 4; ++i) {
        const size_t row = row0 + wm * 64 + mi * 16 + l4 * 4 + i;
        float v = acc[mi][ni][i] + bcol;
        const size_t idx = row * DMODEL + col;
        if (MODE == 1) v *= 0.125f;
        if (MODE == 2) Cf32[idx] = resid[idx] + v;
        else           Cbf[idx]  = f2bf(v);
      }
    }
  }
}

// ---------------------------------------------------------------- flash attention
// grid: (M/64, H, B), 256 threads = 4 waves, wave w owns q-rows [w*16, w*16+16)
__global__ __launch_bounds__(256)
void attn_kernel(const unsigned short* __restrict__ qb,
                 const unsigned short* __restrict__ kb,
                 const unsigned short* __restrict__ vb,
                 const float* __restrict__ lgb,
                 unsigned short* __restrict__ attn)
{
  __shared__ unsigned short Qs[64 * 64];
  __shared__ unsigned short Ks[64 * 64];
  __shared__ unsigned short VTs[64 * 64];
  __shared__ unsigned short Ps[4][16 * 64];

  const int tid  = threadIdx.x;
  const int wave = tid >> 6;
  const int lane = tid & 63;
  const int l15  = lane & 15;
  const int l4   = lane >> 4;
  const int m0   = blockIdx.x * 64;
  const int h    = blockIdx.y;
  const int b    = blockIdx.z;

  const unsigned short* qg = qb + ((size_t)(b * MM + m0)) * DMODEL + h * DHEAD;
  const unsigned short* kg = kb + ((size_t)(b * NN)) * DMODEL + h * DHEAD;
  const unsigned short* vg = vb + ((size_t)(b * NN)) * DMODEL + h * DHEAD;

  // stage Q (64x64 bf16, 8KB): linear LDS dest, pre-swizzled global source
#pragma unroll
  for (int is = 0; is < 2; ++is) {
    int cc = (wave * 2 + is) * 64 + lane;   // 0..511
    int r  = cc >> 3;
    int ch = cc & 7;
    __builtin_amdgcn_global_load_lds(
        (const __attribute__((address_space(1))) void*)(qg + (size_t)r * DMODEL + ((ch ^ (r & 7)) << 3)),
        (__attribute__((address_space(3))) void*)(&Qs[cc * 8]), 16, 0, 0);
  }
  __syncthreads();

  // hoist Q A-fragments: row = wave*16 + l15, k-chunk = ks*4 + l4
  bf16x8 qf[2];
#pragma unroll
  for (int ks = 0; ks < 2; ++ks) {
    int r = wave * 16 + l15;
    qf[ks] = *(const bf16x8*)&Qs[r * 64 + (((ks * 4 + l4) ^ (r & 7)) << 3)];
  }

  f32x4 ovec[4] = {};
  float mrow[4] = {-1e30f, -1e30f, -1e30f, -1e30f};
  float lrow[4] = {0.f, 0.f, 0.f, 0.f};

  for (int nt = 0; nt < NN / 64; ++nt) {
    const int n0 = nt * 64;
    __syncthreads();   // protect K/VT from overwrite while others still compute

    // stage K tile (64 n x 64 d)
#pragma unroll
    for (int is = 0; is < 2; ++is) {
      int cc = (wave * 2 + is) * 64 + lane;
      int r  = cc >> 3;
      int ch = cc & 7;
      __builtin_amdgcn_global_load_lds(
          (const __attribute__((address_space(1))) void*)(kg + (size_t)(n0 + r) * DMODEL + ((ch ^ (r & 7)) << 3)),
          (__attribute__((address_space(3))) void*)(&Ks[cc * 8]), 16, 0, 0);
    }
    // stage V transposed: VTs[d][n] = v[n0+n][d]
    {
      int n  = tid >> 2;
      int d0 = (tid & 3) << 4;
      const unsigned short* src = vg + (size_t)(n0 + n) * DMODEL + d0;
      unsigned short buf[16];
      *(uint4*)&buf[0] = *(const uint4*)(src);
      *(uint4*)&buf[8] = *(const uint4*)(src + 8);
#pragma unroll
      for (int j = 0; j < 16; ++j) {
        int d = d0 + j;
        VTs[d * 64 + (((n >> 3) ^ (d & 7)) << 3) + (n & 7)] = buf[j];
      }
    }
    __syncthreads();

    // S = q*0.125 @ K^T  (16x64 per wave)   C layout: col(n)=l15, row(m)=l4*4+i
    f32x4 s[4] = {};
#pragma unroll
    for (int ni = 0; ni < 4; ++ni) {
      int n = ni * 16 + l15;
#pragma unroll
      for (int ks = 0; ks < 2; ++ks) {
        bf16x8 kf = *(const bf16x8*)&Ks[n * 64 + (((ks * 4 + l4) ^ (n & 7)) << 3)];
        s[ni] = __builtin_amdgcn_mfma_f32_16x16x32_bf16(qf[ks], kf, s[ni], 0, 0, 0);
      }
    }
    // + gate bias (per n)
#pragma unroll
    for (int ni = 0; ni < 4; ++ni) {
      float g = lgb[(size_t)b * NN + n0 + ni * 16 + l15];
#pragma unroll
      for (int i = 0; i < 4; ++i) s[ni][i] += g;
    }

    // online softmax: reduce over the 16-lane col group (same l4 => same rows)
    float tm[4];
#pragma unroll
    for (int i = 0; i < 4; ++i)
      tm[i] = fmaxf(fmaxf(s[0][i], s[1][i]), fmaxf(s[2][i], s[3][i]));
#pragma unroll
    for (int mask = 1; mask < 16; mask <<= 1)
#pragma unroll
      for (int i = 0; i < 4; ++i) tm[i] = fmaxf(tm[i], __shfl_xor(tm[i], mask));

    float alpha[4];
#pragma unroll
    for (int i = 0; i < 4; ++i) {
      float mn = fmaxf(mrow[i], tm[i]);
      alpha[i] = __expf(mrow[i] - mn);
      mrow[i] = mn;
    }
    float rs[4] = {0.f, 0.f, 0.f, 0.f};
#pragma unroll
    for (int ni = 0; ni < 4; ++ni)
#pragma unroll
      for (int i = 0; i < 4; ++i) {
        float p = __expf(s[ni][i] - mrow[i]);
        s[ni][i] = p;
        rs[i] += p;
      }
#pragma unroll
    for (int mask = 1; mask < 16; mask <<= 1)
#pragma unroll
      for (int i = 0; i < 4; ++i) rs[i] += __shfl_xor(rs[i], mask);
#pragma unroll
    for (int i = 0; i < 4; ++i) lrow[i] = lrow[i] * alpha[i] + rs[i];

    // write P (bf16) to wave-private LDS tile [16 m][64 n] (swizzled)
    unsigned short* Pw = &Ps[wave][0];
#pragma unroll
    for (int ni = 0; ni < 4; ++ni) {
      int n = ni * 16 + l15;
#pragma unroll
      for (int i = 0; i < 4; ++i) {
        int r = l4 * 4 + i;
        Pw[r * 64 + (((n >> 3) ^ (r & 7)) << 3) + (n & 7)] = f2bf(s[ni][i]);
      }
    }
    // rescale O
#pragma unroll
    for (int di = 0; di < 4; ++di)
#pragma unroll
      for (int i = 0; i < 4; ++i) ovec[di][i] *= alpha[i];

    // O += P @ V  : A-frag from Pw (row=l15), B-frag from VTs[d][n]
#pragma unroll
    for (int ks2 = 0; ks2 < 2; ++ks2) {
      bf16x8 pf = *(const bf16x8*)&Pw[l15 * 64 + (((ks2 * 4 + l4) ^ (l15 & 7)) << 3)];
#pragma unroll
      for (int di = 0; di < 4; ++di) {
        int d = di * 16 + l15;
        bf16x8 vf = *(const bf16x8*)&VTs[d * 64 + (((ks2 * 4 + l4) ^ (d & 7)) << 3)];
        ovec[di] = __builtin_amdgcn_mfma_f32_16x16x32_bf16(pf, vf, ovec[di], 0, 0, 0);
      }
    }
  }

  // normalize + store
  float inv[4];
#pragma unroll
  for (int i = 0; i < 4; ++i) inv[i] = 1.0f / lrow[i];
#pragma unroll
  for (int di = 0; di < 4; ++di)
#pragma unroll
    for (int i = 0; i < 4; ++i) {
      int row = m0 + wave * 16 + l4 * 4 + i;
      int col = h * DHEAD + di * 16 + l15;
      attn[((size_t)(b * MM + row)) * DMODEL + col] = f2bf(ovec[di][i] * inv[i]);
    }
}

// ---------------------------------------------------------------- LayerNorm (1 row / block)
__global__ __launch_bounds__(256)
void ln_kernel(const float* __restrict__ x, const float* __restrict__ gamma,
               const float* __restrict__ beta, float* __restrict__ out)
{
  __shared__ float sh1[4], sh2[4];
  const int t = threadIdx.x;
  const size_t row = blockIdx.x;
  const float4 v = ((const float4*)(x + row * DMODEL))[t];

  float s = v.x + v.y + v.z + v.w;
#pragma unroll
  for (int m = 1; m < 64; m <<= 1) s += __shfl_xor(s, m);
  if ((t & 63) == 0) sh1[t >> 6] = s;
  __syncthreads();
  const float mu = (sh1[0] + sh1[1] + sh1[2] + sh1[3]) * (1.0f / DMODEL);

  const float dx = v.x - mu, dy = v.y - mu, dz = v.z - mu, dw = v.w - mu;
  float q = dx * dx + dy * dy + dz * dz + dw * dw;
#pragma unroll
  for (int m = 1; m < 64; m <<= 1) q += __shfl_xor(q, m);
  if ((t & 63) == 0) sh2[t >> 6] = q;
  __syncthreads();
  const float var = (sh2[0] + sh2[1] + sh2[2] + sh2[3]) * (1.0f / DMODEL);
  const float rstd = rsqrtf(var + 1e-5f);

  const float4 g  = ((const float4*)gamma)[t];
  const float4 be = ((const float4*)beta)[t];
  float4 o;
  o.x = dx * rstd * g.x + be.x;
  o.y = dy * rstd * g.y + be.y;
  o.z = dz * rstd * g.z + be.z;
  o.w = dw * rstd * g.w + be.w;
  ((float4*)(out + row * DMODEL))[t] = o;
}

// ---------------------------------------------------------------- launch
extern "C" void kernel_launch(void* const* d_in, const int* in_sizes, int n_in,
                              void* d_out, int out_size, void* d_ws, size_t ws_size,
                              hipStream_t stream)
{
  const float* Qf    = (const float*)d_in[0];
  const float* KVf   = (const float*)d_in[1];
  const float* lgb   = (const float*)d_in[2];
  const float* Wq    = (const float*)d_in[3];
  const float* bq    = (const float*)d_in[4];
  const float* Wk    = (const float*)d_in[5];
  const float* bk    = (const float*)d_in[6];
  const float* Wv    = (const float*)d_in[7];
  const float* bv    = (const float*)d_in[8];
  const float* Wo    = (const float*)d_in[9];
  const float* bo    = (const float*)d_in[10];
  const float* gamma = (const float*)d_in[11];
  const float* beta  = (const float*)d_in[12];
  float* out = (float*)d_out;

  char* ws = (char*)d_ws;
  // region A (8 MB): Q bf16, later reused for attention output (bf16)
  unsigned short* Qbf  = (unsigned short*)(ws + 0);
  unsigned short* attnb = Qbf;
  // region B (16 MB): KV bf16, later reused for x (fp32, pre-LN)
  unsigned short* KVbf = (unsigned short*)(ws + 8388608);
  float*          xbuf = (float*)(ws + 8388608);
  // weights bf16 (4 x 2 MB)
  unsigned short* Wqb = (unsigned short*)(ws + 25165824);
  unsigned short* Wkb = (unsigned short*)(ws + 27262976);
  unsigned short* Wvb = (unsigned short*)(ws + 29360128);
  unsigned short* Wob = (unsigned short*)(ws + 31457280);
  // activations bf16
  unsigned short* qbuf = (unsigned short*)(ws + 33554432);  // 8 MB
  unsigned short* kbuf = (unsigned short*)(ws + 41943040);  // 16 MB
  unsigned short* vbuf = (unsigned short*)(ws + 58720256);  // 16 MB

  dim3 blk(256);
  cast_kernel<<<4096, blk, 0, stream>>>(Qf,  Qbf,  1048576);
  cast_kernel<<<8192, blk, 0, stream>>>(KVf, KVbf, 2097152);
  cast_kernel<<<1024, blk, 0, stream>>>(Wq, Wqb, 262144);
  cast_kernel<<<1024, blk, 0, stream>>>(Wk, Wkb, 262144);
  cast_kernel<<<1024, blk, 0, stream>>>(Wv, Wvb, 262144);
  cast_kernel<<<1024, blk, 0, stream>>>(Wo, Wob, 262144);

  gemm_bt<1><<<dim3(32, 8), blk, 0, stream>>>(Qbf,  Wqb, bq, nullptr, qbuf, nullptr);
  gemm_bt<0><<<dim3(64, 8), blk, 0, stream>>>(KVbf, Wkb, bk, nullptr, kbuf, nullptr);
  gemm_bt<0><<<dim3(64, 8), blk, 0, stream>>>(KVbf, Wvb, bv, nullptr, vbuf, nullptr);

  attn_kernel<<<dim3(16, 16, 4), blk, 0, stream>>>(qbuf, kbuf, vbuf, lgb, attnb);

  gemm_bt<2><<<dim3(32, 8), blk, 0, stream>>>(attnb, Wob, bo, Qf, nullptr, xbuf);

  ln_kernel<<<4096, blk, 0, stream>>>(xbuf, gamma, beta, out);
}

// Round 2
// 288.993 us; speedup vs baseline: 1.0083x; 1.0083x over previous
//
#include <hip/hip_runtime.h>
#include <hip/hip_bf16.h>

#define DMODEL 1024
#define NHEAD  16
#define DHEAD  64
#define BB     4
#define MM     1024
#define NN     2048

typedef __attribute__((ext_vector_type(8))) short bf16x8;
typedef __attribute__((ext_vector_type(4))) float f32x4;

#define AS1 __attribute__((address_space(1)))
#define AS3 __attribute__((address_space(3)))

__device__ __forceinline__ unsigned short f2bf(float f) {
  unsigned int u = __builtin_bit_cast(unsigned int, f);
  unsigned int r = (u + 0x7fffu + ((u >> 16) & 1u)) >> 16;
  return (unsigned short)r;
}

// ---------------------------------------------------------------- cast f32 -> bf16
__global__ __launch_bounds__(256)
void cast_kernel(const float* __restrict__ src, unsigned short* __restrict__ dst, int n4) {
  int i = blockIdx.x * 256 + threadIdx.x;
  if (i >= n4) return;
  const float4 v = ((const float4*)src)[i];
  union { unsigned short us[4]; unsigned long long u64; } o;
  o.us[0] = f2bf(v.x); o.us[1] = f2bf(v.y); o.us[2] = f2bf(v.z); o.us[3] = f2bf(v.w);
  *(unsigned long long*)(dst + (size_t)i * 4) = o.u64;
}

// fused 4-weight cast (each weight: 1M floats = 262144 float4, 1024 blocks each)
__global__ __launch_bounds__(256)
void cast4_kernel(const float* __restrict__ w0, const float* __restrict__ w1,
                  const float* __restrict__ w2, const float* __restrict__ w3,
                  unsigned short* __restrict__ o0, unsigned short* __restrict__ o1,
                  unsigned short* __restrict__ o2, unsigned short* __restrict__ o3) {
  const int which = blockIdx.x >> 10;
  const float* s = which == 0 ? w0 : which == 1 ? w1 : which == 2 ? w2 : w3;
  unsigned short* d = which == 0 ? o0 : which == 1 ? o1 : which == 2 ? o2 : o3;
  const int i = (blockIdx.x & 1023) * 256 + threadIdx.x;
  const float4 v = ((const float4*)s)[i];
  union { unsigned short us[4]; unsigned long long u64; } o;
  o.us[0] = f2bf(v.x); o.us[1] = f2bf(v.y); o.us[2] = f2bf(v.z); o.us[3] = f2bf(v.w);
  *(unsigned long long*)(d + (size_t)i * 4) = o.u64;
}

// ---------------------------------------------------------------- GEMM  C = A @ W^T (+bias)
template<int MODE>
__global__ __launch_bounds__(256)
void gemm_bt(const unsigned short* __restrict__ A,
             const unsigned short* __restrict__ W,
             const float* __restrict__ bias,
             const float* __restrict__ resid,
             unsigned short* __restrict__ Cbf,
             float* __restrict__ Cf32)
{
  __shared__ unsigned short As[2][128 * 32];
  __shared__ unsigned short Ws[2][128 * 32];

  const int tid  = threadIdx.x;
  const int wave = tid >> 6;
  const int lane = tid & 63;
  const int l15  = lane & 15;
  const int l4   = lane >> 4;
  const int wm   = wave >> 1;
  const int wn   = wave & 1;
  const size_t row0 = (size_t)blockIdx.x * 128;
  const size_t col0 = (size_t)blockIdx.y * 128;

  f32x4 acc[4][4] = {};

  auto stage = [&](int buf, int kt) {
    const unsigned short* Ab = A + row0 * DMODEL + kt * 32;
    const unsigned short* Wb = W + col0 * DMODEL + kt * 32;
#pragma unroll
    for (int is = 0; is < 2; ++is) {
      int cc  = (wave * 2 + is) * 64 + lane;
      int r   = cc >> 2;
      int ch  = cc & 3;
      int sch = ch ^ (r & 3);
      __builtin_amdgcn_global_load_lds(
          (const AS1 void*)(Ab + (size_t)r * DMODEL + sch * 8),
          (AS3 void*)(&As[buf][cc * 8]), 16, 0, 0);
      __builtin_amdgcn_global_load_lds(
          (const AS1 void*)(Wb + (size_t)r * DMODEL + sch * 8),
          (AS3 void*)(&Ws[buf][cc * 8]), 16, 0, 0);
    }
  };

  stage(0, 0);
  __syncthreads();

  for (int kt = 0; kt < 32; ++kt) {
    const int cur = kt & 1;
    if (kt < 31) stage(cur ^ 1, kt + 1);

    bf16x8 af[4], bfr[4];
#pragma unroll
    for (int mi = 0; mi < 4; ++mi) {
      int r = wm * 64 + mi * 16 + l15;
      af[mi] = *(const bf16x8*)&As[cur][r * 32 + ((l4 ^ (r & 3)) << 3)];
    }
#pragma unroll
    for (int ni = 0; ni < 4; ++ni) {
      int r = wn * 64 + ni * 16 + l15;
      bfr[ni] = *(const bf16x8*)&Ws[cur][r * 32 + ((l4 ^ (r & 3)) << 3)];
    }
#pragma unroll
    for (int mi = 0; mi < 4; ++mi)
#pragma unroll
      for (int ni = 0; ni < 4; ++ni)
        acc[mi][ni] = __builtin_amdgcn_mfma_f32_16x16x32_bf16(af[mi], bfr[ni], acc[mi][ni], 0, 0, 0);

    __syncthreads();
  }

#pragma unroll
  for (int mi = 0; mi < 4; ++mi) {
#pragma unroll
    for (int ni = 0; ni < 4; ++ni) {
      const int col = (int)col0 + wn * 64 + ni * 16 + l15;
      const float bcol = bias[col];
#pragma unroll
      for (int i = 0; i < 4; ++i) {
        const size_t row = row0 + wm * 64 + mi * 16 + l4 * 4 + i;
        float v = acc[mi][ni][i] + bcol;
        const size_t idx = row * DMODEL + col;
        if (MODE == 1) v *= 0.125f;
        if (MODE == 2) Cf32[idx] = resid[idx] + v;
        else           Cbf[idx]  = f2bf(v);
      }
    }
  }
}

// ---------------------------------------------------------------- V transpose
// vbuf [B][N][H*DH] -> vt [B*H][DH=64][N=2048]    grid (N/64, B*H), 256 thr
__global__ __launch_bounds__(256)
void transpose_v(const unsigned short* __restrict__ v, unsigned short* __restrict__ vt)
{
  __shared__ unsigned short t[64 * 72];   // [d][n'] stride 72, n' = n ^ (8*(d>>3))
  const int tid = threadIdx.x;
  const int bh  = blockIdx.y;
  const int b   = bh >> 4;
  const int h   = bh & 15;
  const int n0  = blockIdx.x * 64;

  // read: 16B = 8 d's for one n; scalar-write transposed into LDS
#pragma unroll
  for (int it = 0; it < 2; ++it) {
    const int c2  = tid + it * 256;
    const int n   = c2 >> 3;          // 0..63
    const int dch = c2 & 7;           // d-chunk
    const unsigned short* src = v + ((size_t)(b * NN + n0 + n)) * DMODEL + h * DHEAD + dch * 8;
    unsigned short buf[8];
    *(uint4*)buf = *(const uint4*)src;
#pragma unroll
    for (int j = 0; j < 8; ++j) {
      const int d = dch * 8 + j;
      t[d * 72 + (n ^ (8 * (d >> 3)))] = buf[j];
    }
  }
  __syncthreads();

  // write: 16B = 8 n's for one d, coalesced to global
#pragma unroll
  for (int it = 0; it < 2; ++it) {
    const int c2 = tid + it * 256;
    const int d  = c2 >> 3;           // 0..63
    const int c  = c2 & 7;            // n-chunk
    const uint4 val = *(const uint4*)&t[d * 72 + ((c ^ (d >> 3)) << 3)];
    *(uint4*)(vt + ((size_t)bh * 64 + d) * NN + n0 + c * 8) = val;
  }
}

// ---------------------------------------------------------------- flash attention
// grid: (M/64, H, B), 256 threads = 4 waves; wave w owns q-rows [w*16, w*16+16)
__global__ __launch_bounds__(256)
void attn_kernel(const unsigned short* __restrict__ qb,
                 const unsigned short* __restrict__ kb,
                 const unsigned short* __restrict__ vt,
                 const float* __restrict__ lgb,
                 unsigned short* __restrict__ attn)
{
  __shared__ unsigned short Ks[2][64 * 64];
  __shared__ unsigned short Vs[2][64 * 64];
  __shared__ float Gs[2][64];
  __shared__ unsigned short Ps[4][16 * 64];

  const int tid  = threadIdx.x;
  const int wave = tid >> 6;
  const int lane = tid & 63;
  const int l15  = lane & 15;
  const int l4   = lane >> 4;
  const int m0   = blockIdx.x * 64;
  const int h    = blockIdx.y;
  const int b    = blockIdx.z;

  const unsigned short* qg = qb + ((size_t)(b * MM + m0)) * DMODEL + h * DHEAD;
  const unsigned short* kg = kb + ((size_t)b * NN) * DMODEL + h * DHEAD;
  const unsigned short* vg = vt + ((size_t)(b * NHEAD + h)) * (DHEAD * (size_t)NN);
  const float* gg = lgb + (size_t)b * NN;

  // Q fragments straight from global (row = wave*16+l15, k-chunk = l4)
  bf16x8 qf[2];
  {
    const unsigned short* qrow = qg + (size_t)(wave * 16 + l15) * DMODEL;
    qf[0] = *(const bf16x8*)(qrow + l4 * 8);
    qf[1] = *(const bf16x8*)(qrow + 32 + l4 * 8);
  }

  auto stageKV = [&](int buf, int nt) {
    const int n0 = nt * 64;
    if (wave == 0)
      __builtin_amdgcn_global_load_lds((const AS1 void*)(gg + n0 + lane),
                                       (AS3 void*)(&Gs[buf][lane]), 4, 0, 0);
#pragma unroll
    for (int is = 0; is < 2; ++is) {
      int cc = (wave * 2 + is) * 64 + lane;   // 0..511
      int r  = cc >> 3;                        // row 0..63
      int ch = cc & 7;
      __builtin_amdgcn_global_load_lds(
          (const AS1 void*)(kg + (size_t)(n0 + r) * DMODEL + ((ch ^ (r & 7)) << 3)),
          (AS3 void*)(&Ks[buf][cc * 8]), 16, 0, 0);
    }
#pragma unroll
    for (int is = 0; is < 2; ++is) {
      int cc = (wave * 2 + is) * 64 + lane;
      int r  = cc >> 3;                        // row = d 0..63
      int ch = cc & 7;
      __builtin_amdgcn_global_load_lds(
          (const AS1 void*)(vg + (size_t)r * NN + n0 + ((ch ^ (r & 7)) << 3)),
          (AS3 void*)(&Vs[buf][cc * 8]), 16, 0, 0);
    }
  };

  stageKV(0, 0);

  f32x4 ovec[4] = {};
  float mrow[4] = {-1e30f, -1e30f, -1e30f, -1e30f};
  float lrow[4] = {0.f, 0.f, 0.f, 0.f};
  unsigned short* Pw = &Ps[wave][0];

  for (int nt = 0; nt < NN / 64; ++nt) {
    const int cur = nt & 1;
    if (nt < NN / 64 - 1) {
      stageKV(cur ^ 1, nt + 1);
      if (wave == 0) asm volatile("s_waitcnt vmcnt(5)" ::: "memory");
      else           asm volatile("s_waitcnt vmcnt(4)" ::: "memory");
    } else {
      asm volatile("s_waitcnt vmcnt(0)" ::: "memory");
    }
    __builtin_amdgcn_sched_barrier(0);
    __builtin_amdgcn_s_barrier();
    __builtin_amdgcn_sched_barrier(0);

    // S = q*0.125 @ K^T   C layout: col(n)=l15, row(m)=l4*4+i
    f32x4 s[4] = {};
    __builtin_amdgcn_s_setprio(1);
#pragma unroll
    for (int ni = 0; ni < 4; ++ni) {
      int n = ni * 16 + l15;
#pragma unroll
      for (int ks = 0; ks < 2; ++ks) {
        bf16x8 kf = *(const bf16x8*)&Ks[cur][n * 64 + (((ks * 4 + l4) ^ (n & 7)) << 3)];
        s[ni] = __builtin_amdgcn_mfma_f32_16x16x32_bf16(qf[ks], kf, s[ni], 0, 0, 0);
      }
    }
    __builtin_amdgcn_s_setprio(0);

    // + gate bias (from LDS)
#pragma unroll
    for (int ni = 0; ni < 4; ++ni) {
      float g = Gs[cur][ni * 16 + l15];
#pragma unroll
      for (int i = 0; i < 4; ++i) s[ni][i] += g;
    }

    // online softmax over n (16-lane col groups share rows)
    float tm[4];
#pragma unroll
    for (int i = 0; i < 4; ++i)
      tm[i] = fmaxf(fmaxf(s[0][i], s[1][i]), fmaxf(s[2][i], s[3][i]));
#pragma unroll
    for (int mask = 1; mask < 16; mask <<= 1)
#pragma unroll
      for (int i = 0; i < 4; ++i) tm[i] = fmaxf(tm[i], __shfl_xor(tm[i], mask));

    float alpha[4];
#pragma unroll
    for (int i = 0; i < 4; ++i) {
      float mn = fmaxf(mrow[i], tm[i]);
      alpha[i] = __expf(mrow[i] - mn);
      mrow[i] = mn;
    }
    float rs[4] = {0.f, 0.f, 0.f, 0.f};
#pragma unroll
    for (int ni = 0; ni < 4; ++ni)
#pragma unroll
      for (int i = 0; i < 4; ++i) {
        float p = __expf(s[ni][i] - mrow[i]);
        s[ni][i] = p;
        rs[i] += p;
      }
#pragma unroll
    for (int mask = 1; mask < 16; mask <<= 1)
#pragma unroll
      for (int i = 0; i < 4; ++i) rs[i] += __shfl_xor(rs[i], mask);
#pragma unroll
    for (int i = 0; i < 4; ++i) lrow[i] = lrow[i] * alpha[i] + rs[i];

    // P -> wave-private LDS tile (swizzled)
#pragma unroll
    for (int ni = 0; ni < 4; ++ni) {
      int n = ni * 16 + l15;
#pragma unroll
      for (int i = 0; i < 4; ++i) {
        int r = l4 * 4 + i;
        Pw[r * 64 + (((n >> 3) ^ (r & 7)) << 3) + (n & 7)] = f2bf(s[ni][i]);
      }
    }
    // rescale O
#pragma unroll
    for (int di = 0; di < 4; ++di)
#pragma unroll
      for (int i = 0; i < 4; ++i) ovec[di][i] *= alpha[i];

    // O += P @ V  (B-frag from V^T rows)
    __builtin_amdgcn_s_setprio(1);
#pragma unroll
    for (int ks2 = 0; ks2 < 2; ++ks2) {
      bf16x8 pf = *(const bf16x8*)&Pw[l15 * 64 + (((ks2 * 4 + l4) ^ (l15 & 7)) << 3)];
#pragma unroll
      for (int di = 0; di < 4; ++di) {
        int d = di * 16 + l15;
        bf16x8 vf = *(const bf16x8*)&Vs[cur][d * 64 + (((ks2 * 4 + l4) ^ (d & 7)) << 3)];
        ovec[di] = __builtin_amdgcn_mfma_f32_16x16x32_bf16(pf, vf, ovec[di], 0, 0, 0);
      }
    }
    __builtin_amdgcn_s_setprio(0);

    __builtin_amdgcn_s_barrier();
    __builtin_amdgcn_sched_barrier(0);
  }

  // normalize + store
  float inv[4];
#pragma unroll
  for (int i = 0; i < 4; ++i) inv[i] = 1.0f / lrow[i];
#pragma unroll
  for (int di = 0; di < 4; ++di)
#pragma unroll
    for (int i = 0; i < 4; ++i) {
      int row = m0 + wave * 16 + l4 * 4 + i;
      int col = h * DHEAD + di * 16 + l15;
      attn[((size_t)(b * MM + row)) * DMODEL + col] = f2bf(ovec[di][i] * inv[i]);
    }
}

// ---------------------------------------------------------------- LayerNorm (1 row / block)
__global__ __launch_bounds__(256)
void ln_kernel(const float* __restrict__ x, const float* __restrict__ gamma,
               const float* __restrict__ beta, float* __restrict__ out)
{
  __shared__ float sh1[4], sh2[4];
  const int t = threadIdx.x;
  const size_t row = blockIdx.x;
  const float4 v = ((const float4*)(x + row * DMODEL))[t];

  float s = v.x + v.y + v.z + v.w;
#pragma unroll
  for (int m = 1; m < 64; m <<= 1) s += __shfl_xor(s, m);
  if ((t & 63) == 0) sh1[t >> 6] = s;
  __syncthreads();
  const float mu = (sh1[0] + sh1[1] + sh1[2] + sh1[3]) * (1.0f / DMODEL);

  const float dx = v.x - mu, dy = v.y - mu, dz = v.z - mu, dw = v.w - mu;
  float q = dx * dx + dy * dy + dz * dz + dw * dw;
#pragma unroll
  for (int m = 1; m < 64; m <<= 1) q += __shfl_xor(q, m);
  if ((t & 63) == 0) sh2[t >> 6] = q;
  __syncthreads();
  const float var = (sh2[0] + sh2[1] + sh2[2] + sh2[3]) * (1.0f / DMODEL);
  const float rstd = rsqrtf(var + 1e-5f);

  const float4 g  = ((const float4*)gamma)[t];
  const float4 be = ((const float4*)beta)[t];
  float4 o;
  o.x = dx * rstd * g.x + be.x;
  o.y = dy * rstd * g.y + be.y;
  o.z = dz * rstd * g.z + be.z;
  o.w = dw * rstd * g.w + be.w;
  ((float4*)(out + row * DMODEL))[t] = o;
}

// ---------------------------------------------------------------- launch
extern "C" void kernel_launch(void* const* d_in, const int* in_sizes, int n_in,
                              void* d_out, int out_size, void* d_ws, size_t ws_size,
                              hipStream_t stream)
{
  const float* Qf    = (const float*)d_in[0];
  const float* KVf   = (const float*)d_in[1];
  const float* lgb   = (const float*)d_in[2];
  const float* Wq    = (const float*)d_in[3];
  const float* bq    = (const float*)d_in[4];
  const float* Wk    = (const float*)d_in[5];
  const float* bk    = (const float*)d_in[6];
  const float* Wv    = (const float*)d_in[7];
  const float* bv    = (const float*)d_in[8];
  const float* Wo    = (const float*)d_in[9];
  const float* bo    = (const float*)d_in[10];
  const float* gamma = (const float*)d_in[11];
  const float* beta  = (const float*)d_in[12];
  float* out = (float*)d_out;

  char* ws = (char*)d_ws;
  // region A (8 MB): Q bf16, later attention output (bf16)
  unsigned short* Qbf   = (unsigned short*)(ws + 0);
  unsigned short* attnb = Qbf;
  // region B (16 MB): KV bf16 -> V^T bf16 -> x fp32 (each lifetime disjoint)
  unsigned short* KVbf  = (unsigned short*)(ws + 8388608);
  unsigned short* vtbuf = (unsigned short*)(ws + 8388608);
  float*          xbuf  = (float*)(ws + 8388608);
  // weights bf16 (4 x 2 MB)
  unsigned short* Wqb = (unsigned short*)(ws + 25165824);
  unsigned short* Wkb = (unsigned short*)(ws + 27262976);
  unsigned short* Wvb = (unsigned short*)(ws + 29360128);
  unsigned short* Wob = (unsigned short*)(ws + 31457280);
  // activations bf16
  unsigned short* qbuf = (unsigned short*)(ws + 33554432);  // 8 MB
  unsigned short* kbuf = (unsigned short*)(ws + 41943040);  // 16 MB
  unsigned short* vbuf = (unsigned short*)(ws + 58720256);  // 16 MB

  dim3 blk(256);
  cast_kernel<<<4096, blk, 0, stream>>>(Qf,  Qbf,  1048576);
  cast_kernel<<<8192, blk, 0, stream>>>(KVf, KVbf, 2097152);
  cast4_kernel<<<4096, blk, 0, stream>>>(Wq, Wk, Wv, Wo, Wqb, Wkb, Wvb, Wob);

  gemm_bt<1><<<dim3(32, 8), blk, 0, stream>>>(Qbf,  Wqb, bq, nullptr, qbuf, nullptr);
  gemm_bt<0><<<dim3(64, 8), blk, 0, stream>>>(KVbf, Wkb, bk, nullptr, kbuf, nullptr);
  gemm_bt<0><<<dim3(64, 8), blk, 0, stream>>>(KVbf, Wvb, bv, nullptr, vbuf, nullptr);

  transpose_v<<<dim3(32, 64), blk, 0, stream>>>(vbuf, vtbuf);

  attn_kernel<<<dim3(16, 16, 4), blk, 0, stream>>>(qbuf, kbuf, vtbuf, lgb, attnb);

  gemm_bt<2><<<dim3(32, 8), blk, 0, stream>>>(attnb, Wob, bo, Qf, nullptr, xbuf);

  ln_kernel<<<4096, blk, 0, stream>>>(xbuf, gamma, beta, out);
}

// Round 3
// 245.426 us; speedup vs baseline: 1.1873x; 1.1775x over previous
//
#include <hip/hip_runtime.h>
#include <hip/hip_bf16.h>

#define DMODEL 1024
#define NHEAD  16
#define DHEAD  64
#define BB     4
#define MM     1024
#define NN     2048
#define LOG2E  1.4426950408889634f

typedef __attribute__((ext_vector_type(8))) short bf16x8;
typedef __attribute__((ext_vector_type(4))) float f32x4;

#define AS1 __attribute__((address_space(1)))
#define AS3 __attribute__((address_space(3)))

__device__ __forceinline__ unsigned short f2bf(float f) {
  unsigned int u = __builtin_bit_cast(unsigned int, f);
  unsigned int r = (u + 0x7fffu + ((u >> 16) & 1u)) >> 16;
  return (unsigned short)r;
}

// ---------------------------------------------------------------- cast f32 -> bf16
__global__ __launch_bounds__(256)
void cast_kernel(const float* __restrict__ src, unsigned short* __restrict__ dst, int n4) {
  int i = blockIdx.x * 256 + threadIdx.x;
  if (i >= n4) return;
  const float4 v = ((const float4*)src)[i];
  union { unsigned short us[4]; unsigned long long u64; } o;
  o.us[0] = f2bf(v.x); o.us[1] = f2bf(v.y); o.us[2] = f2bf(v.z); o.us[3] = f2bf(v.w);
  *(unsigned long long*)(dst + (size_t)i * 4) = o.u64;
}

__global__ __launch_bounds__(256)
void cast4_kernel(const float* __restrict__ w0, const float* __restrict__ w1,
                  const float* __restrict__ w2, const float* __restrict__ w3,
                  unsigned short* __restrict__ o0, unsigned short* __restrict__ o1,
                  unsigned short* __restrict__ o2, unsigned short* __restrict__ o3) {
  const int which = blockIdx.x >> 10;
  const float* s = which == 0 ? w0 : which == 1 ? w1 : which == 2 ? w2 : w3;
  unsigned short* d = which == 0 ? o0 : which == 1 ? o1 : which == 2 ? o2 : o3;
  const int i = (blockIdx.x & 1023) * 256 + threadIdx.x;
  const float4 v = ((const float4*)s)[i];
  union { unsigned short us[4]; unsigned long long u64; } o;
  o.us[0] = f2bf(v.x); o.us[1] = f2bf(v.y); o.us[2] = f2bf(v.z); o.us[3] = f2bf(v.w);
  *(unsigned long long*)(d + (size_t)i * 4) = o.u64;
}

// ---------------------------------------------------------------- GEMM  C = A @ W^T (+bias)
// MODE 0: Cbf = bf16(acc + bias)
// MODE 1: Cbf = bf16((acc + bias) * 0.125 * log2e)   (pre-scaled q, log2-domain)
// MODE 2: Cf32 = resid + acc + bias                  (fp32 x for LayerNorm)
template<int MODE>
__global__ __launch_bounds__(256)
void gemm_bt(const unsigned short* __restrict__ A,
             const unsigned short* __restrict__ W,
             const float* __restrict__ bias,
             const float* __restrict__ resid,
             unsigned short* __restrict__ Cbf,
             float* __restrict__ Cf32)
{
  __shared__ unsigned short As[2][128 * 32];
  __shared__ unsigned short Ws[2][128 * 32];

  const int tid  = threadIdx.x;
  const int wave = tid >> 6;
  const int lane = tid & 63;
  const int l15  = lane & 15;
  const int l4   = lane >> 4;
  const int wm   = wave >> 1;
  const int wn   = wave & 1;
  const size_t row0 = (size_t)blockIdx.x * 128;
  const size_t col0 = (size_t)blockIdx.y * 128;

  f32x4 acc[4][4] = {};

  auto stage = [&](int buf, int kt) {
    const unsigned short* Ab = A + row0 * DMODEL + kt * 32;
    const unsigned short* Wb = W + col0 * DMODEL + kt * 32;
#pragma unroll
    for (int is = 0; is < 2; ++is) {
      int cc  = (wave * 2 + is) * 64 + lane;
      int r   = cc >> 2;
      int ch  = cc & 3;
      int sch = ch ^ (r & 3);
      __builtin_amdgcn_global_load_lds(
          (const AS1 void*)(Ab + (size_t)r * DMODEL + sch * 8),
          (AS3 void*)(&As[buf][cc * 8]), 16, 0, 0);
      __builtin_amdgcn_global_load_lds(
          (const AS1 void*)(Wb + (size_t)r * DMODEL + sch * 8),
          (AS3 void*)(&Ws[buf][cc * 8]), 16, 0, 0);
    }
  };

  stage(0, 0);
  __syncthreads();

  for (int kt = 0; kt < 32; ++kt) {
    const int cur = kt & 1;
    if (kt < 31) stage(cur ^ 1, kt + 1);

    bf16x8 af[4], bfr[4];
#pragma unroll
    for (int mi = 0; mi < 4; ++mi) {
      int r = wm * 64 + mi * 16 + l15;
      af[mi] = *(const bf16x8*)&As[cur][r * 32 + ((l4 ^ (r & 3)) << 3)];
    }
#pragma unroll
    for (int ni = 0; ni < 4; ++ni) {
      int r = wn * 64 + ni * 16 + l15;
      bfr[ni] = *(const bf16x8*)&Ws[cur][r * 32 + ((l4 ^ (r & 3)) << 3)];
    }
#pragma unroll
    for (int mi = 0; mi < 4; ++mi)
#pragma unroll
      for (int ni = 0; ni < 4; ++ni)
        acc[mi][ni] = __builtin_amdgcn_mfma_f32_16x16x32_bf16(af[mi], bfr[ni], acc[mi][ni], 0, 0, 0);

    __syncthreads();
  }

#pragma unroll
  for (int mi = 0; mi < 4; ++mi) {
#pragma unroll
    for (int ni = 0; ni < 4; ++ni) {
      const int col = (int)col0 + wn * 64 + ni * 16 + l15;
      const float bcol = bias[col];
#pragma unroll
      for (int i = 0; i < 4; ++i) {
        const size_t row = row0 + wm * 64 + mi * 16 + l4 * 4 + i;
        float v = acc[mi][ni][i] + bcol;
        const size_t idx = row * DMODEL + col;
        if (MODE == 1) v *= (0.125f * LOG2E);
        if (MODE == 2) Cf32[idx] = resid[idx] + v;
        else Cbf[idx] = __builtin_bit_cast(unsigned short, __float2bfloat16(v));
      }
    }
  }
}

// ---------------------------------------------------------------- V transpose
__global__ __launch_bounds__(256)
void transpose_v(const unsigned short* __restrict__ v, unsigned short* __restrict__ vt)
{
  __shared__ unsigned short t[64 * 72];
  const int tid = threadIdx.x;
  const int bh  = blockIdx.y;
  const int b   = bh >> 4;
  const int h   = bh & 15;
  const int n0  = blockIdx.x * 64;

#pragma unroll
  for (int it = 0; it < 2; ++it) {
    const int c2  = tid + it * 256;
    const int n   = c2 >> 3;
    const int dch = c2 & 7;
    const unsigned short* src = v + ((size_t)(b * NN + n0 + n)) * DMODEL + h * DHEAD + dch * 8;
    unsigned short buf[8];
    *(uint4*)buf = *(const uint4*)src;
#pragma unroll
    for (int j = 0; j < 8; ++j) {
      const int d = dch * 8 + j;
      t[d * 72 + (n ^ (8 * (d >> 3)))] = buf[j];
    }
  }
  __syncthreads();

#pragma unroll
  for (int it = 0; it < 2; ++it) {
    const int c2 = tid + it * 256;
    const int d  = c2 >> 3;
    const int c  = c2 & 7;
    const uint4 val = *(const uint4*)&t[d * 72 + ((c ^ (d >> 3)) << 3)];
    *(uint4*)(vt + ((size_t)bh * 64 + d) * NN + n0 + c * 8) = val;
  }
}

// ---------------------------------------------------------------- flash attention
// flat grid 1024 blocks; XCD-grouped: all 16 m-blocks of one (b,h) share an XCD.
// Swapped QK^T: lane owns q-row l15; l via ones-column MFMA; defer-max rescale.
__global__ __launch_bounds__(256, 3)
void attn_kernel(const unsigned short* __restrict__ qb,
                 const unsigned short* __restrict__ kb,
                 const unsigned short* __restrict__ vt,
                 const float* __restrict__ lgb,
                 unsigned short* __restrict__ attn)
{
  __shared__ unsigned short Ks[2][64 * 64];
  __shared__ unsigned short Vs[2][64 * 64];
  __shared__ float Gs[2][64];
  __shared__ unsigned short Ps[4][16 * 64];

  const int tid  = threadIdx.x;
  const int wave = tid >> 6;
  const int lane = tid & 63;
  const int l15  = lane & 15;
  const int l4   = lane >> 4;

  const int bid  = blockIdx.x;
  const int xcd  = bid & 7;
  const int slot = bid >> 3;
  const int m_i  = slot & 15;
  const int grp  = slot >> 4;
  const int bh   = grp * 8 + xcd;      // all m-blocks of bh -> same xcd
  const int b    = bh >> 4;
  const int h    = bh & 15;
  const int m0   = m_i * 64;

  const unsigned short* qg = qb + ((size_t)(b * MM + m0)) * DMODEL + h * DHEAD;
  const unsigned short* kg = kb + ((size_t)b * NN) * DMODEL + h * DHEAD;
  const unsigned short* vg = vt + ((size_t)(b * NHEAD + h)) * (DHEAD * (size_t)NN);
  const float* gg = lgb + (size_t)b * NN;

  // Q B-fragments from global: row m = wave*16 + l15, d-chunk = l4 (+4)
  bf16x8 qf0, qf1;
  {
    const unsigned short* qrow = qg + (size_t)(wave * 16 + l15) * DMODEL;
    qf0 = *(const bf16x8*)(qrow + l4 * 8);
    qf1 = *(const bf16x8*)(qrow + 32 + l4 * 8);
  }

  // ones-column B-fragment: row d'=l15 -> 1.0 only for l15==0
  bf16x8 ones;
  {
    const short one = (l15 == 0) ? (short)0x3f80 : (short)0;
#pragma unroll
    for (int j = 0; j < 8; ++j) ones[j] = one;
  }

  auto stageKV = [&](int buf, int nt) {
    const int n0 = nt * 64;
    __builtin_amdgcn_global_load_lds((const AS1 void*)(gg + n0 + lane),
                                     (AS3 void*)(&Gs[buf][lane]), 4, 0, 0);
#pragma unroll
    for (int is = 0; is < 2; ++is) {
      int cc = (wave * 2 + is) * 64 + lane;
      int r  = cc >> 3;
      int ch = cc & 7;
      __builtin_amdgcn_global_load_lds(
          (const AS1 void*)(kg + (size_t)(n0 + r) * DMODEL + ((ch ^ (r & 7)) << 3)),
          (AS3 void*)(&Ks[buf][cc * 8]), 16, 0, 0);
    }
#pragma unroll
    for (int is = 0; is < 2; ++is) {
      int cc = (wave * 2 + is) * 64 + lane;
      int r  = cc >> 3;
      int ch = cc & 7;
      __builtin_amdgcn_global_load_lds(
          (const AS1 void*)(vg + (size_t)r * NN + n0 + ((ch ^ (r & 7)) << 3)),
          (AS3 void*)(&Vs[buf][cc * 8]), 16, 0, 0);
    }
  };

  stageKV(0, 0);

  f32x4 ovec[5] = {};            // 4 O d-tiles + 1 l-column tile
  float mrow = -1e30f;
  unsigned short* Pw = &Ps[wave][0];
  const int pbase = l15 * 128;
  const int s7 = l15 & 7;

  for (int nt = 0; nt < NN / 64; ++nt) {
    const int cur = nt & 1;
    asm volatile("s_waitcnt vmcnt(0)" ::: "memory");
    __builtin_amdgcn_s_barrier();
    __builtin_amdgcn_sched_barrier(0);
    if (nt < NN / 64 - 1) stageKV(cur ^ 1, nt + 1);

    // S^T tile: s[ni][i] = S[m = l15 (+wave*16)][n = ni*16 + l4*4 + i]
    f32x4 s[4];
    __builtin_amdgcn_s_setprio(1);
#pragma unroll
    for (int ni = 0; ni < 4; ++ni) {
      const int r = ni * 16 + l15;
      const int c0 = l4 ^ (r & 7);
      bf16x8 kf0 = *(const bf16x8*)&Ks[cur][r * 64 + (c0 << 3)];
      bf16x8 kf1 = *(const bf16x8*)&Ks[cur][r * 64 + ((c0 ^ 4) << 3)];
      f32x4 z = {};
      z = __builtin_amdgcn_mfma_f32_16x16x32_bf16(kf0, qf0, z, 0, 0, 0);
      s[ni] = __builtin_amdgcn_mfma_f32_16x16x32_bf16(kf1, qf1, z, 0, 0, 0);
    }
    __builtin_amdgcn_s_setprio(0);

    // gate (log2-domain) + tile max
    float tmax = -1e30f;
#pragma unroll
    for (int ni = 0; ni < 4; ++ni) {
      const float4 g = *(const float4*)&Gs[cur][ni * 16 + l4 * 4];
      s[ni][0] = fmaf(g.x, LOG2E, s[ni][0]);
      s[ni][1] = fmaf(g.y, LOG2E, s[ni][1]);
      s[ni][2] = fmaf(g.z, LOG2E, s[ni][2]);
      s[ni][3] = fmaf(g.w, LOG2E, s[ni][3]);
      tmax = fmaxf(tmax, fmaxf(fmaxf(s[ni][0], s[ni][1]), fmaxf(s[ni][2], s[ni][3])));
    }
    tmax = fmaxf(tmax, __shfl_xor(tmax, 16));
    tmax = fmaxf(tmax, __shfl_xor(tmax, 32));

    // defer-max: rescale only when some row's max grew (wave vote)
    if (!__all(tmax <= mrow)) {
      const float mnew  = fmaxf(mrow, tmax);
      const float alpha = __builtin_amdgcn_exp2f(mrow - mnew);
      mrow = mnew;
      const int abase = l4 << 2;
#pragma unroll
      for (int i = 0; i < 4; ++i) {
        const float ai = __shfl(alpha, abase + i);   // alpha of q-row l4*4+i
        ovec[0][i] *= ai; ovec[1][i] *= ai; ovec[2][i] *= ai;
        ovec[3][i] *= ai; ovec[4][i] *= ai;
      }
    }

    // p = exp2(s - m), pack bf16, write P (swizzled, wave-private)
#pragma unroll
    for (int ni = 0; ni < 4; ++ni) {
      union { unsigned short us[4]; uint2 u; } pk;
#pragma unroll
      for (int i = 0; i < 4; ++i)
        pk.us[i] = __builtin_bit_cast(unsigned short,
                     __float2bfloat16(__builtin_amdgcn_exp2f(s[ni][i] - mrow)));
      *(uint2*)((char*)Pw + pbase + (((ni * 4 + l4) ^ (s7 << 1)) << 3)) = pk.u;
    }
    asm volatile("s_waitcnt lgkmcnt(0)" ::: "memory");
    __builtin_amdgcn_sched_barrier(0);

    // O += P @ V ; l += P @ 1
    __builtin_amdgcn_s_setprio(1);
#pragma unroll
    for (int ks2 = 0; ks2 < 2; ++ks2) {
      const bf16x8 pf = *(const bf16x8*)((const char*)Pw + pbase + (((ks2 * 4 + l4) ^ s7) << 4));
#pragma unroll
      for (int di = 0; di < 4; ++di) {
        const int d = di * 16 + l15;
        const bf16x8 vf = *(const bf16x8*)&Vs[cur][d * 64 + (((ks2 * 4 + l4) ^ (d & 7)) << 3)];
        ovec[di] = __builtin_amdgcn_mfma_f32_16x16x32_bf16(pf, vf, ovec[di], 0, 0, 0);
      }
      ovec[4] = __builtin_amdgcn_mfma_f32_16x16x32_bf16(pf, ones, ovec[4], 0, 0, 0);
    }
    __builtin_amdgcn_s_setprio(0);
  }

  // l broadcast (held by lanes l15==0) + normalize + store
  const int lsrc = lane & 48;
  float linv[4];
#pragma unroll
  for (int i = 0; i < 4; ++i)
    linv[i] = 1.0f / __shfl(ovec[4][i], lsrc);
#pragma unroll
  for (int di = 0; di < 4; ++di)
#pragma unroll
    for (int i = 0; i < 4; ++i) {
      const int row = m0 + wave * 16 + l4 * 4 + i;
      const int col = h * DHEAD + di * 16 + l15;
      attn[((size_t)(b * MM + row)) * DMODEL + col] =
        __builtin_bit_cast(unsigned short, __float2bfloat16(ovec[di][i] * linv[i]));
    }
}

// ---------------------------------------------------------------- LayerNorm
__global__ __launch_bounds__(256)
void ln_kernel(const float* __restrict__ x, const float* __restrict__ gamma,
               const float* __restrict__ beta, float* __restrict__ out)
{
  __shared__ float sh1[4], sh2[4];
  const int t = threadIdx.x;
  const size_t row = blockIdx.x;
  const float4 v = ((const float4*)(x + row * DMODEL))[t];

  float s = v.x + v.y + v.z + v.w;
#pragma unroll
  for (int m = 1; m < 64; m <<= 1) s += __shfl_xor(s, m);
  if ((t & 63) == 0) sh1[t >> 6] = s;
  __syncthreads();
  const float mu = (sh1[0] + sh1[1] + sh1[2] + sh1[3]) * (1.0f / DMODEL);

  const float dx = v.x - mu, dy = v.y - mu, dz = v.z - mu, dw = v.w - mu;
  float q = dx * dx + dy * dy + dz * dz + dw * dw;
#pragma unroll
  for (int m = 1; m < 64; m <<= 1) q += __shfl_xor(q, m);
  if ((t & 63) == 0) sh2[t >> 6] = q;
  __syncthreads();
  const float var = (sh2[0] + sh2[1] + sh2[2] + sh2[3]) * (1.0f / DMODEL);
  const float rstd = rsqrtf(var + 1e-5f);

  const float4 g  = ((const float4*)gamma)[t];
  const float4 be = ((const float4*)beta)[t];
  float4 o;
  o.x = dx * rstd * g.x + be.x;
  o.y = dy * rstd * g.y + be.y;
  o.z = dz * rstd * g.z + be.z;
  o.w = dw * rstd * g.w + be.w;
  ((float4*)(out + row * DMODEL))[t] = o;
}

// ---------------------------------------------------------------- launch
extern "C" void kernel_launch(void* const* d_in, const int* in_sizes, int n_in,
                              void* d_out, int out_size, void* d_ws, size_t ws_size,
                              hipStream_t stream)
{
  const float* Qf    = (const float*)d_in[0];
  const float* KVf   = (const float*)d_in[1];
  const float* lgb   = (const float*)d_in[2];
  const float* Wq    = (const float*)d_in[3];
  const float* bq    = (const float*)d_in[4];
  const float* Wk    = (const float*)d_in[5];
  const float* bk    = (const float*)d_in[6];
  const float* Wv    = (const float*)d_in[7];
  const float* bv    = (const float*)d_in[8];
  const float* Wo    = (const float*)d_in[9];
  const float* bo    = (const float*)d_in[10];
  const float* gamma = (const float*)d_in[11];
  const float* beta  = (const float*)d_in[12];
  float* out = (float*)d_out;

  char* ws = (char*)d_ws;
  unsigned short* Qbf   = (unsigned short*)(ws + 0);
  unsigned short* attnb = Qbf;
  unsigned short* KVbf  = (unsigned short*)(ws + 8388608);
  unsigned short* vtbuf = (unsigned short*)(ws + 8388608);
  float*          xbuf  = (float*)(ws + 8388608);
  unsigned short* Wqb = (unsigned short*)(ws + 25165824);
  unsigned short* Wkb = (unsigned short*)(ws + 27262976);
  unsigned short* Wvb = (unsigned short*)(ws + 29360128);
  unsigned short* Wob = (unsigned short*)(ws + 31457280);
  unsigned short* qbuf = (unsigned short*)(ws + 33554432);
  unsigned short* kbuf = (unsigned short*)(ws + 41943040);
  unsigned short* vbuf = (unsigned short*)(ws + 58720256);

  dim3 blk(256);
  cast_kernel<<<4096, blk, 0, stream>>>(Qf,  Qbf,  1048576);
  cast_kernel<<<8192, blk, 0, stream>>>(KVf, KVbf, 2097152);
  cast4_kernel<<<4096, blk, 0, stream>>>(Wq, Wk, Wv, Wo, Wqb, Wkb, Wvb, Wob);

  gemm_bt<1><<<dim3(32, 8), blk, 0, stream>>>(Qbf,  Wqb, bq, nullptr, qbuf, nullptr);
  gemm_bt<0><<<dim3(64, 8), blk, 0, stream>>>(KVbf, Wkb, bk, nullptr, kbuf, nullptr);
  gemm_bt<0><<<dim3(64, 8), blk, 0, stream>>>(KVbf, Wvb, bv, nullptr, vbuf, nullptr);

  transpose_v<<<dim3(32, 64), blk, 0, stream>>>(vbuf, vtbuf);

  attn_kernel<<<1024, blk, 0, stream>>>(qbuf, kbuf, vtbuf, lgb, attnb);

  gemm_bt<2><<<dim3(32, 8), blk, 0, stream>>>(attnb, Wob, bo, Qf, nullptr, xbuf);

  ln_kernel<<<4096, blk, 0, stream>>>(xbuf, gamma, beta, out);
}

// Round 4
// 192.544 us; speedup vs baseline: 1.5135x; 1.2747x over previous
//
#include <hip/hip_runtime.h>
#include <hip/hip_bf16.h>

#define DMODEL 1024
#define NHEAD  16
#define DHEAD  64
#define BB     4
#define MM     1024
#define NN     2048
#define LOG2E  1.4426950408889634f

typedef __attribute__((ext_vector_type(8))) short bf16x8;
typedef __attribute__((ext_vector_type(4))) float f32x4;

#define AS1 __attribute__((address_space(1)))
#define AS3 __attribute__((address_space(3)))

__device__ __forceinline__ unsigned short f2bf(float f) {
  unsigned int u = __builtin_bit_cast(unsigned int, f);
  unsigned int r = (u + 0x7fffu + ((u >> 16) & 1u)) >> 16;
  return (unsigned short)r;
}

// ---------------------------------------------------------------- fused cast f32 -> bf16
// blocks: [0,4096) Q ; [4096,12288) KV ; [12288,16384) four weights (1024 each)
__global__ __launch_bounds__(256)
void cast_all(const float* __restrict__ Q, const float* __restrict__ KV,
              const float* __restrict__ W0, const float* __restrict__ W1,
              const float* __restrict__ W2, const float* __restrict__ W3,
              unsigned short* __restrict__ oQ, unsigned short* __restrict__ oKV,
              unsigned short* __restrict__ o0, unsigned short* __restrict__ o1,
              unsigned short* __restrict__ o2, unsigned short* __restrict__ o3)
{
  const int bid = blockIdx.x;
  const float* s; unsigned short* d; int i;
  if (bid < 4096)       { s = Q;  d = oQ;  i = bid * 256 + threadIdx.x; }
  else if (bid < 12288) { s = KV; d = oKV; i = (bid - 4096) * 256 + threadIdx.x; }
  else {
    const int w = (bid - 12288) >> 10;
    s = w == 0 ? W0 : w == 1 ? W1 : w == 2 ? W2 : W3;
    d = w == 0 ? o0 : w == 1 ? o1 : w == 2 ? o2 : o3;
    i = ((bid - 12288) & 1023) * 256 + threadIdx.x;
  }
  const float4 v = ((const float4*)s)[i];
  union { unsigned short us[4]; unsigned long long u64; } o;
  o.us[0] = f2bf(v.x); o.us[1] = f2bf(v.y); o.us[2] = f2bf(v.z); o.us[3] = f2bf(v.w);
  *(unsigned long long*)(d + (size_t)i * 4) = o.u64;
}

// ---------------------------------------------------------------- fused QKV GEMM
// flat grid 1280: [0,256) q-proj (scaled), [256,768) k-proj, [768,1280) v-proj -> V^T
__global__ __launch_bounds__(256)
void qkv_gemm(const unsigned short* __restrict__ Qbf,
              const unsigned short* __restrict__ KVbf,
              const unsigned short* __restrict__ Wqb,
              const unsigned short* __restrict__ Wkb,
              const unsigned short* __restrict__ Wvb,
              const float* __restrict__ bq, const float* __restrict__ bk,
              const float* __restrict__ bv,
              unsigned short* __restrict__ qout,
              unsigned short* __restrict__ kout,
              unsigned short* __restrict__ vtout)
{
  __shared__ unsigned short As[2][128 * 32];
  __shared__ unsigned short Ws[2][128 * 32];

  const int bid = blockIdx.x;
  const unsigned short* A; const unsigned short* W; const float* bias;
  int mode, mb, nb;
  if (bid < 256)      { A = Qbf;  W = Wqb; bias = bq; mode = 0; mb = bid >> 3;        nb = bid & 7; }
  else if (bid < 768) { A = KVbf; W = Wkb; bias = bk; mode = 1; mb = (bid - 256) >> 3; nb = bid & 7; }
  else                { A = KVbf; W = Wvb; bias = bv; mode = 2; mb = (bid - 768) >> 3; nb = bid & 7; }

  const int tid  = threadIdx.x;
  const int wave = tid >> 6;
  const int lane = tid & 63;
  const int l15  = lane & 15;
  const int l4   = lane >> 4;
  const int wm   = wave >> 1;
  const int wn   = wave & 1;
  const size_t row0 = (size_t)mb * 128;
  const size_t col0 = (size_t)nb * 128;

  f32x4 acc[4][4] = {};

  auto stage = [&](int buf, int kt) {
    const unsigned short* Ab = A + row0 * DMODEL + kt * 32;
    const unsigned short* Wb = W + col0 * DMODEL + kt * 32;
#pragma unroll
    for (int is = 0; is < 2; ++is) {
      int cc  = (wave * 2 + is) * 64 + lane;
      int r   = cc >> 2;
      int ch  = cc & 3;
      int sch = ch ^ (r & 3);
      __builtin_amdgcn_global_load_lds(
          (const AS1 void*)(Ab + (size_t)r * DMODEL + sch * 8),
          (AS3 void*)(&As[buf][cc * 8]), 16, 0, 0);
      __builtin_amdgcn_global_load_lds(
          (const AS1 void*)(Wb + (size_t)r * DMODEL + sch * 8),
          (AS3 void*)(&Ws[buf][cc * 8]), 16, 0, 0);
    }
  };

  stage(0, 0);
  __syncthreads();

  for (int kt = 0; kt < 32; ++kt) {
    const int cur = kt & 1;
    if (kt < 31) stage(cur ^ 1, kt + 1);

    bf16x8 af[4], bfr[4];
#pragma unroll
    for (int mi = 0; mi < 4; ++mi) {
      int r = wm * 64 + mi * 16 + l15;
      af[mi] = *(const bf16x8*)&As[cur][r * 32 + ((l4 ^ (r & 3)) << 3)];
    }
#pragma unroll
    for (int ni = 0; ni < 4; ++ni) {
      int r = wn * 64 + ni * 16 + l15;
      bfr[ni] = *(const bf16x8*)&Ws[cur][r * 32 + ((l4 ^ (r & 3)) << 3)];
    }
#pragma unroll
    for (int mi = 0; mi < 4; ++mi)
#pragma unroll
      for (int ni = 0; ni < 4; ++ni)
        acc[mi][ni] = __builtin_amdgcn_mfma_f32_16x16x32_bf16(af[mi], bfr[ni], acc[mi][ni], 0, 0, 0);

    __syncthreads();
  }

#pragma unroll
  for (int mi = 0; mi < 4; ++mi) {
#pragma unroll
    for (int ni = 0; ni < 4; ++ni) {
      const int col = (int)col0 + wn * 64 + ni * 16 + l15;
      const float bcol = bias[col];
      if (mode == 2) {
        // V^T epilogue: pack 4 consecutive n (i) as uint2 -> vt[(b*16+h)][d][n]
        const int row = (int)row0 + wm * 64 + mi * 16 + l4 * 4;
        const int b = row >> 11, n = row & 2047;
        const int h = col >> 6, d = col & 63;
        union { unsigned short us[4]; uint2 u; } pk;
#pragma unroll
        for (int i = 0; i < 4; ++i)
          pk.us[i] = __builtin_bit_cast(unsigned short, __float2bfloat16(acc[mi][ni][i] + bcol));
        *(uint2*)(vtout + (((size_t)(b * 16 + h) * 64 + d) << 11) + n) = pk.u;
      } else {
#pragma unroll
        for (int i = 0; i < 4; ++i) {
          const size_t row = row0 + wm * 64 + mi * 16 + l4 * 4 + i;
          float v = acc[mi][ni][i] + bcol;
          if (mode == 0) v *= (0.125f * LOG2E);
          (mode == 0 ? qout : kout)[row * DMODEL + col] =
            __builtin_bit_cast(unsigned short, __float2bfloat16(v));
        }
      }
    }
  }
}

// ---------------------------------------------------------------- o-proj GEMM (64x128 tile)
// Cf32 = resid + A@W^T + bias     grid (64, 8)
__global__ __launch_bounds__(256)
void gemm_o(const unsigned short* __restrict__ A,
            const unsigned short* __restrict__ W,
            const float* __restrict__ bias,
            const float* __restrict__ resid,
            float* __restrict__ out)
{
  __shared__ unsigned short As[2][64 * 32];
  __shared__ unsigned short Ws[2][128 * 32];

  const int tid  = threadIdx.x;
  const int wave = tid >> 6;
  const int lane = tid & 63;
  const int l15  = lane & 15;
  const int l4   = lane >> 4;
  const int wm   = wave >> 1;
  const int wn   = wave & 1;
  const size_t row0 = (size_t)blockIdx.x * 64;
  const size_t col0 = (size_t)blockIdx.y * 128;

  f32x4 acc[2][4] = {};

  auto stage = [&](int buf, int kt) {
    const unsigned short* Ab = A + row0 * DMODEL + kt * 32;
    const unsigned short* Wb = W + col0 * DMODEL + kt * 32;
    {
      int cc  = tid;                 // 256 chunks for 64x32 A-tile
      int r   = cc >> 2;
      int ch  = cc & 3;
      int sch = ch ^ (r & 3);
      __builtin_amdgcn_global_load_lds(
          (const AS1 void*)(Ab + (size_t)r * DMODEL + sch * 8),
          (AS3 void*)(&As[buf][cc * 8]), 16, 0, 0);
    }
#pragma unroll
    for (int is = 0; is < 2; ++is) {
      int cc  = (wave * 2 + is) * 64 + lane;
      int r   = cc >> 2;
      int ch  = cc & 3;
      int sch = ch ^ (r & 3);
      __builtin_amdgcn_global_load_lds(
          (const AS1 void*)(Wb + (size_t)r * DMODEL + sch * 8),
          (AS3 void*)(&Ws[buf][cc * 8]), 16, 0, 0);
    }
  };

  stage(0, 0);
  __syncthreads();

  for (int kt = 0; kt < 32; ++kt) {
    const int cur = kt & 1;
    if (kt < 31) stage(cur ^ 1, kt + 1);

    bf16x8 af[2], bfr[4];
#pragma unroll
    for (int mi = 0; mi < 2; ++mi) {
      int r = wm * 32 + mi * 16 + l15;
      af[mi] = *(const bf16x8*)&As[cur][r * 32 + ((l4 ^ (r & 3)) << 3)];
    }
#pragma unroll
    for (int ni = 0; ni < 4; ++ni) {
      int r = wn * 64 + ni * 16 + l15;
      bfr[ni] = *(const bf16x8*)&Ws[cur][r * 32 + ((l4 ^ (r & 3)) << 3)];
    }
#pragma unroll
    for (int mi = 0; mi < 2; ++mi)
#pragma unroll
      for (int ni = 0; ni < 4; ++ni)
        acc[mi][ni] = __builtin_amdgcn_mfma_f32_16x16x32_bf16(af[mi], bfr[ni], acc[mi][ni], 0, 0, 0);

    __syncthreads();
  }

#pragma unroll
  for (int mi = 0; mi < 2; ++mi) {
#pragma unroll
    for (int ni = 0; ni < 4; ++ni) {
      const int col = (int)col0 + wn * 64 + ni * 16 + l15;
      const float bcol = bias[col];
#pragma unroll
      for (int i = 0; i < 4; ++i) {
        const size_t row = row0 + wm * 32 + mi * 16 + l4 * 4 + i;
        const size_t idx = row * DMODEL + col;
        out[idx] = resid[idx] + acc[mi][ni][i] + bcol;
      }
    }
  }
}

// ---------------------------------------------------------------- flash attention
// flat grid 1024; XCD-grouped; swapped QK^T; l via ones-column; defer-max;
// gate bias prefetched into registers (no LDS) -> 40960B LDS = 4 blocks/CU.
__global__ __launch_bounds__(256, 4)
void attn_kernel(const unsigned short* __restrict__ qb,
                 const unsigned short* __restrict__ kb,
                 const unsigned short* __restrict__ vt,
                 const float* __restrict__ lgb,
                 unsigned short* __restrict__ attn)
{
  __shared__ unsigned short Ks[2][64 * 64];
  __shared__ unsigned short Vs[2][64 * 64];
  __shared__ unsigned short Ps[4][16 * 64];

  const int tid  = threadIdx.x;
  const int wave = tid >> 6;
  const int lane = tid & 63;
  const int l15  = lane & 15;
  const int l4   = lane >> 4;

  const int bid  = blockIdx.x;
  const int xcd  = bid & 7;
  const int slot = bid >> 3;
  const int m_i  = slot & 15;
  const int grp  = slot >> 4;
  const int bh   = grp * 8 + xcd;
  const int b    = bh >> 4;
  const int h    = bh & 15;
  const int m0   = m_i * 64;

  const unsigned short* qg = qb + ((size_t)(b * MM + m0)) * DMODEL + h * DHEAD;
  const unsigned short* kg = kb + ((size_t)b * NN) * DMODEL + h * DHEAD;
  const unsigned short* vg = vt + ((size_t)(b * NHEAD + h)) * (DHEAD * (size_t)NN);
  const float* gg = lgb + (size_t)b * NN;

  bf16x8 qf0, qf1;
  {
    const unsigned short* qrow = qg + (size_t)(wave * 16 + l15) * DMODEL;
    qf0 = *(const bf16x8*)(qrow + l4 * 8);
    qf1 = *(const bf16x8*)(qrow + 32 + l4 * 8);
  }

  bf16x8 ones;
  {
    const short one = (l15 == 0) ? (short)0x3f80 : (short)0;
#pragma unroll
    for (int j = 0; j < 8; ++j) ones[j] = one;
  }

  auto stageKV = [&](int buf, int nt) {
    const int n0 = nt * 64;
#pragma unroll
    for (int is = 0; is < 2; ++is) {
      int cc = (wave * 2 + is) * 64 + lane;
      int r  = cc >> 3;
      int ch = cc & 7;
      __builtin_amdgcn_global_load_lds(
          (const AS1 void*)(kg + (size_t)(n0 + r) * DMODEL + ((ch ^ (r & 7)) << 3)),
          (AS3 void*)(&Ks[buf][cc * 8]), 16, 0, 0);
    }
#pragma unroll
    for (int is = 0; is < 2; ++is) {
      int cc = (wave * 2 + is) * 64 + lane;
      int r  = cc >> 3;
      int ch = cc & 7;
      __builtin_amdgcn_global_load_lds(
          (const AS1 void*)(vg + (size_t)r * NN + n0 + ((ch ^ (r & 7)) << 3)),
          (AS3 void*)(&Vs[buf][cc * 8]), 16, 0, 0);
    }
  };

  // gate prefetch (registers)
  f32x4 gc[4], gn[4];
#pragma unroll
  for (int ni = 0; ni < 4; ++ni)
    gc[ni] = *(const f32x4*)&gg[ni * 16 + l4 * 4];

  stageKV(0, 0);

  f32x4 ovec[5] = {};
  float mrow = -1e30f;
  unsigned short* Pw = &Ps[wave][0];
  const int pbase = l15 * 128;
  const int s7 = l15 & 7;

  for (int nt = 0; nt < NN / 64; ++nt) {
    const int cur = nt & 1;
    asm volatile("s_waitcnt vmcnt(0)" ::: "memory");
    __builtin_amdgcn_s_barrier();
    __builtin_amdgcn_sched_barrier(0);
    if (nt < NN / 64 - 1) {
      stageKV(cur ^ 1, nt + 1);
#pragma unroll
      for (int ni = 0; ni < 4; ++ni)
        gn[ni] = *(const f32x4*)&gg[(nt + 1) * 64 + ni * 16 + l4 * 4];
    }

    // S^T tile: s[ni][i] = S[m = l15][n = ni*16 + l4*4 + i]
    f32x4 s[4];
    __builtin_amdgcn_s_setprio(1);
#pragma unroll
    for (int ni = 0; ni < 4; ++ni) {
      const int r = ni * 16 + l15;
      const int c0 = l4 ^ (r & 7);
      bf16x8 kf0 = *(const bf16x8*)&Ks[cur][r * 64 + (c0 << 3)];
      bf16x8 kf1 = *(const bf16x8*)&Ks[cur][r * 64 + ((c0 ^ 4) << 3)];
      f32x4 z = {};
      z = __builtin_amdgcn_mfma_f32_16x16x32_bf16(kf0, qf0, z, 0, 0, 0);
      s[ni] = __builtin_amdgcn_mfma_f32_16x16x32_bf16(kf1, qf1, z, 0, 0, 0);
    }
    __builtin_amdgcn_s_setprio(0);

    // gate (log2-domain, from regs) + tile max
    float tmax = -1e30f;
#pragma unroll
    for (int ni = 0; ni < 4; ++ni) {
#pragma unroll
      for (int i = 0; i < 4; ++i)
        s[ni][i] = fmaf(gc[ni][i], LOG2E, s[ni][i]);
      tmax = fmaxf(tmax, fmaxf(fmaxf(s[ni][0], s[ni][1]), fmaxf(s[ni][2], s[ni][3])));
    }
    tmax = fmaxf(tmax, __shfl_xor(tmax, 16));
    tmax = fmaxf(tmax, __shfl_xor(tmax, 32));

    if (!__all(tmax <= mrow)) {
      const float mnew  = fmaxf(mrow, tmax);
      const float alpha = __builtin_amdgcn_exp2f(mrow - mnew);
      mrow = mnew;
      const int abase = l4 << 2;
#pragma unroll
      for (int i = 0; i < 4; ++i) {
        const float ai = __shfl(alpha, abase + i);
        ovec[0][i] *= ai; ovec[1][i] *= ai; ovec[2][i] *= ai;
        ovec[3][i] *= ai; ovec[4][i] *= ai;
      }
    }

    // p = exp2(s - m), pack bf16, write P (swizzled, wave-private)
#pragma unroll
    for (int ni = 0; ni < 4; ++ni) {
      union { unsigned short us[4]; uint2 u; } pk;
#pragma unroll
      for (int i = 0; i < 4; ++i)
        pk.us[i] = __builtin_bit_cast(unsigned short,
                     __float2bfloat16(__builtin_amdgcn_exp2f(s[ni][i] - mrow)));
      *(uint2*)((char*)Pw + pbase + (((ni * 4 + l4) ^ (s7 << 1)) << 3)) = pk.u;
    }
    asm volatile("s_waitcnt lgkmcnt(0)" ::: "memory");
    __builtin_amdgcn_sched_barrier(0);

    // O += P @ V ; l += P @ 1
    __builtin_amdgcn_s_setprio(1);
#pragma unroll
    for (int ks2 = 0; ks2 < 2; ++ks2) {
      const bf16x8 pf = *(const bf16x8*)((const char*)Pw + pbase + (((ks2 * 4 + l4) ^ s7) << 4));
#pragma unroll
      for (int di = 0; di < 4; ++di) {
        const int d = di * 16 + l15;
        const bf16x8 vf = *(const bf16x8*)&Vs[cur][d * 64 + (((ks2 * 4 + l4) ^ (d & 7)) << 3)];
        ovec[di] = __builtin_amdgcn_mfma_f32_16x16x32_bf16(pf, vf, ovec[di], 0, 0, 0);
      }
      ovec[4] = __builtin_amdgcn_mfma_f32_16x16x32_bf16(pf, ones, ovec[4], 0, 0, 0);
    }
    __builtin_amdgcn_s_setprio(0);

    if (nt < NN / 64 - 1) {
#pragma unroll
      for (int ni = 0; ni < 4; ++ni) gc[ni] = gn[ni];
    }
  }

  const int lsrc = lane & 48;
  float linv[4];
#pragma unroll
  for (int i = 0; i < 4; ++i)
    linv[i] = 1.0f / __shfl(ovec[4][i], lsrc);
#pragma unroll
  for (int di = 0; di < 4; ++di)
#pragma unroll
    for (int i = 0; i < 4; ++i) {
      const int row = m0 + wave * 16 + l4 * 4 + i;
      const int col = h * DHEAD + di * 16 + l15;
      attn[((size_t)(b * MM + row)) * DMODEL + col] =
        __builtin_bit_cast(unsigned short, __float2bfloat16(ovec[di][i] * linv[i]));
    }
}

// ---------------------------------------------------------------- LayerNorm
__global__ __launch_bounds__(256)
void ln_kernel(const float* __restrict__ x, const float* __restrict__ gamma,
               const float* __restrict__ beta, float* __restrict__ out)
{
  __shared__ float sh1[4], sh2[4];
  const int t = threadIdx.x;
  const size_t row = blockIdx.x;
  const float4 v = ((const float4*)(x + row * DMODEL))[t];

  float s = v.x + v.y + v.z + v.w;
#pragma unroll
  for (int m = 1; m < 64; m <<= 1) s += __shfl_xor(s, m);
  if ((t & 63) == 0) sh1[t >> 6] = s;
  __syncthreads();
  const float mu = (sh1[0] + sh1[1] + sh1[2] + sh1[3]) * (1.0f / DMODEL);

  const float dx = v.x - mu, dy = v.y - mu, dz = v.z - mu, dw = v.w - mu;
  float q = dx * dx + dy * dy + dz * dz + dw * dw;
#pragma unroll
  for (int m = 1; m < 64; m <<= 1) q += __shfl_xor(q, m);
  if ((t & 63) == 0) sh2[t >> 6] = q;
  __syncthreads();
  const float var = (sh2[0] + sh2[1] + sh2[2] + sh2[3]) * (1.0f / DMODEL);
  const float rstd = rsqrtf(var + 1e-5f);

  const float4 g  = ((const float4*)gamma)[t];
  const float4 be = ((const float4*)beta)[t];
  float4 o;
  o.x = dx * rstd * g.x + be.x;
  o.y = dy * rstd * g.y + be.y;
  o.z = dz * rstd * g.z + be.z;
  o.w = dw * rstd * g.w + be.w;
  ((float4*)(out + row * DMODEL))[t] = o;
}

// ---------------------------------------------------------------- launch
extern "C" void kernel_launch(void* const* d_in, const int* in_sizes, int n_in,
                              void* d_out, int out_size, void* d_ws, size_t ws_size,
                              hipStream_t stream)
{
  const float* Qf    = (const float*)d_in[0];
  const float* KVf   = (const float*)d_in[1];
  const float* lgb   = (const float*)d_in[2];
  const float* Wq    = (const float*)d_in[3];
  const float* bq    = (const float*)d_in[4];
  const float* Wk    = (const float*)d_in[5];
  const float* bk    = (const float*)d_in[6];
  const float* Wv    = (const float*)d_in[7];
  const float* bv    = (const float*)d_in[8];
  const float* Wo    = (const float*)d_in[9];
  const float* bo    = (const float*)d_in[10];
  const float* gamma = (const float*)d_in[11];
  const float* beta  = (const float*)d_in[12];
  float* out = (float*)d_out;

  char* ws = (char*)d_ws;
  unsigned short* Qbf   = (unsigned short*)(ws + 0);          // 8 MB; attnb aliases after Q dead
  unsigned short* attnb = Qbf;
  unsigned short* KVbf  = (unsigned short*)(ws + 8388608);    // 16 MB; xbuf aliases after KV dead
  float*          xbuf  = (float*)(ws + 8388608);
  unsigned short* Wqb = (unsigned short*)(ws + 25165824);
  unsigned short* Wkb = (unsigned short*)(ws + 27262976);
  unsigned short* Wvb = (unsigned short*)(ws + 29360128);
  unsigned short* Wob = (unsigned short*)(ws + 31457280);
  unsigned short* qbuf  = (unsigned short*)(ws + 33554432);   // 8 MB
  unsigned short* kbuf  = (unsigned short*)(ws + 41943040);   // 16 MB
  unsigned short* vtbuf = (unsigned short*)(ws + 58720256);   // 16 MB (V^T, written by qkv_gemm)

  dim3 blk(256);
  cast_all<<<16384, blk, 0, stream>>>(Qf, KVf, Wq, Wk, Wv, Wo,
                                      Qbf, KVbf, Wqb, Wkb, Wvb, Wob);

  qkv_gemm<<<1280, blk, 0, stream>>>(Qbf, KVbf, Wqb, Wkb, Wvb,
                                     bq, bk, bv, qbuf, kbuf, vtbuf);

  attn_kernel<<<1024, blk, 0, stream>>>(qbuf, kbuf, vtbuf, lgb, attnb);

  gemm_o<<<dim3(64, 8), blk, 0, stream>>>(attnb, Wob, bo, Qf, xbuf);

  ln_kernel<<<4096, blk, 0, stream>>>(xbuf, gamma, beta, out);
}

// Round 5
// 179.011 us; speedup vs baseline: 1.6279x; 1.0756x over previous
//
#include <hip/hip_runtime.h>
#include <hip/hip_bf16.h>

#define DMODEL 1024
#define NHEAD  16
#define DHEAD  64
#define BB     4
#define MM     1024
#define NN     2048
#define LOG2E  1.4426950408889634f

typedef __attribute__((ext_vector_type(8))) short bf16x8;
typedef __attribute__((ext_vector_type(4))) float f32x4;

#define AS1 __attribute__((address_space(1)))
#define AS3 __attribute__((address_space(3)))

__device__ __forceinline__ unsigned short f2bf(float f) {
  unsigned int u = __builtin_bit_cast(unsigned int, f);
  unsigned int r = (u + 0x7fffu + ((u >> 16) & 1u)) >> 16;
  return (unsigned short)r;
}

// ---------------------------------------------------------------- fused cast f32 -> bf16
// blocks: [0,4096) Q ; [4096,12288) KV ; [12288,16384) four weights (1024 each)
__global__ __launch_bounds__(256)
void cast_all(const float* __restrict__ Q, const float* __restrict__ KV,
              const float* __restrict__ W0, const float* __restrict__ W1,
              const float* __restrict__ W2, const float* __restrict__ W3,
              unsigned short* __restrict__ oQ, unsigned short* __restrict__ oKV,
              unsigned short* __restrict__ o0, unsigned short* __restrict__ o1,
              unsigned short* __restrict__ o2, unsigned short* __restrict__ o3)
{
  const int bid = blockIdx.x;
  const float* s; unsigned short* d; int i;
  if (bid < 4096)       { s = Q;  d = oQ;  i = bid * 256 + threadIdx.x; }
  else if (bid < 12288) { s = KV; d = oKV; i = (bid - 4096) * 256 + threadIdx.x; }
  else {
    const int w = (bid - 12288) >> 10;
    s = w == 0 ? W0 : w == 1 ? W1 : w == 2 ? W2 : W3;
    d = w == 0 ? o0 : w == 1 ? o1 : w == 2 ? o2 : o3;
    i = ((bid - 12288) & 1023) * 256 + threadIdx.x;
  }
  const float4 v = ((const float4*)s)[i];
  union { unsigned short us[4]; unsigned long long u64; } o;
  o.us[0] = f2bf(v.x); o.us[1] = f2bf(v.y); o.us[2] = f2bf(v.z); o.us[3] = f2bf(v.w);
  *(unsigned long long*)(d + (size_t)i * 4) = o.u64;
}

// ---------------------------------------------------------------- fused QKV GEMM
// flat grid 1280: [0,256) q-proj (scaled), [256,768) k-proj, [768,1280) v-proj -> V^T
// XCD-slab mapping: xcd = local_bid & 7 owns a contiguous mb-slab x all 8 nb,
// so the 8 blocks sharing an A row-panel are co-XCD (A L2-reuse x8).
__global__ __launch_bounds__(256)
void qkv_gemm(const unsigned short* __restrict__ Qbf,
              const unsigned short* __restrict__ KVbf,
              const unsigned short* __restrict__ Wqb,
              const unsigned short* __restrict__ Wkb,
              const unsigned short* __restrict__ Wvb,
              const float* __restrict__ bq, const float* __restrict__ bk,
              const float* __restrict__ bv,
              unsigned short* __restrict__ qout,
              unsigned short* __restrict__ kout,
              unsigned short* __restrict__ vtout)
{
  __shared__ unsigned short As[2][128 * 32];
  __shared__ unsigned short Ws[2][128 * 32];

  const int bid = blockIdx.x;
  const unsigned short* A; const unsigned short* W; const float* bias;
  int mode, lb, nmb;
  if (bid < 256)      { A = Qbf;  W = Wqb; bias = bq; mode = 0; lb = bid;       nmb = 4; }
  else if (bid < 768) { A = KVbf; W = Wkb; bias = bk; mode = 1; lb = bid - 256; nmb = 8; }
  else                { A = KVbf; W = Wvb; bias = bv; mode = 2; lb = bid - 768; nmb = 8; }
  const int xcd = lb & 7;
  const int l   = lb >> 3;
  const int mb  = xcd * nmb + (l >> 3);
  const int nb  = l & 7;

  const int tid  = threadIdx.x;
  const int wave = tid >> 6;
  const int lane = tid & 63;
  const int l15  = lane & 15;
  const int l4   = lane >> 4;
  const int wm   = wave >> 1;
  const int wn   = wave & 1;
  const size_t row0 = (size_t)mb * 128;
  const size_t col0 = (size_t)nb * 128;

  f32x4 acc[4][4] = {};

  auto stage = [&](int buf, int kt) {
    const unsigned short* Ab = A + row0 * DMODEL + kt * 32;
    const unsigned short* Wb = W + col0 * DMODEL + kt * 32;
#pragma unroll
    for (int is = 0; is < 2; ++is) {
      int cc  = (wave * 2 + is) * 64 + lane;
      int r   = cc >> 2;
      int ch  = cc & 3;
      int sch = ch ^ (r & 3);
      __builtin_amdgcn_global_load_lds(
          (const AS1 void*)(Ab + (size_t)r * DMODEL + sch * 8),
          (AS3 void*)(&As[buf][cc * 8]), 16, 0, 0);
      __builtin_amdgcn_global_load_lds(
          (const AS1 void*)(Wb + (size_t)r * DMODEL + sch * 8),
          (AS3 void*)(&Ws[buf][cc * 8]), 16, 0, 0);
    }
  };

  stage(0, 0);
  __syncthreads();

  for (int kt = 0; kt < 32; ++kt) {
    const int cur = kt & 1;
    if (kt < 31) stage(cur ^ 1, kt + 1);

    bf16x8 af[4], bfr[4];
#pragma unroll
    for (int mi = 0; mi < 4; ++mi) {
      int r = wm * 64 + mi * 16 + l15;
      af[mi] = *(const bf16x8*)&As[cur][r * 32 + ((l4 ^ (r & 3)) << 3)];
    }
#pragma unroll
    for (int ni = 0; ni < 4; ++ni) {
      int r = wn * 64 + ni * 16 + l15;
      bfr[ni] = *(const bf16x8*)&Ws[cur][r * 32 + ((l4 ^ (r & 3)) << 3)];
    }
#pragma unroll
    for (int mi = 0; mi < 4; ++mi)
#pragma unroll
      for (int ni = 0; ni < 4; ++ni)
        acc[mi][ni] = __builtin_amdgcn_mfma_f32_16x16x32_bf16(af[mi], bfr[ni], acc[mi][ni], 0, 0, 0);

    __syncthreads();
  }

#pragma unroll
  for (int mi = 0; mi < 4; ++mi) {
#pragma unroll
    for (int ni = 0; ni < 4; ++ni) {
      const int col = (int)col0 + wn * 64 + ni * 16 + l15;
      const float bcol = bias[col];
      if (mode == 2) {
        // V^T epilogue: pack 4 consecutive n (i) as uint2 -> vt[(b*16+h)][d][n]
        const int row = (int)row0 + wm * 64 + mi * 16 + l4 * 4;
        const int b = row >> 11, n = row & 2047;
        const int h = col >> 6, d = col & 63;
        union { unsigned short us[4]; uint2 u; } pk;
#pragma unroll
        for (int i = 0; i < 4; ++i)
          pk.us[i] = __builtin_bit_cast(unsigned short, __float2bfloat16(acc[mi][ni][i] + bcol));
        *(uint2*)(vtout + (((size_t)(b * 16 + h) * 64 + d) << 11) + n) = pk.u;
      } else {
#pragma unroll
        for (int i = 0; i < 4; ++i) {
          const size_t row = row0 + wm * 64 + mi * 16 + l4 * 4 + i;
          float v = acc[mi][ni][i] + bcol;
          if (mode == 0) v *= (0.125f * LOG2E);
          (mode == 0 ? qout : kout)[row * DMODEL + col] =
            __builtin_bit_cast(unsigned short, __float2bfloat16(v));
        }
      }
    }
  }
}

// ---------------------------------------------------------------- o-proj GEMM (64x128 tile)
// Cf32 = resid + A@W^T + bias     flat grid 512, XCD-slab mapping (8 mb/XCD)
__global__ __launch_bounds__(256)
void gemm_o(const unsigned short* __restrict__ A,
            const unsigned short* __restrict__ W,
            const float* __restrict__ bias,
            const float* __restrict__ resid,
            float* __restrict__ out)
{
  __shared__ unsigned short As[2][64 * 32];
  __shared__ unsigned short Ws[2][128 * 32];

  const int bid = blockIdx.x;
  const int xcd = bid & 7;
  const int l   = bid >> 3;
  const int mb  = xcd * 8 + (l >> 3);
  const int nb  = l & 7;

  const int tid  = threadIdx.x;
  const int wave = tid >> 6;
  const int lane = tid & 63;
  const int l15  = lane & 15;
  const int l4   = lane >> 4;
  const int wm   = wave >> 1;
  const int wn   = wave & 1;
  const size_t row0 = (size_t)mb * 64;
  const size_t col0 = (size_t)nb * 128;

  f32x4 acc[2][4] = {};

  auto stage = [&](int buf, int kt) {
    const unsigned short* Ab = A + row0 * DMODEL + kt * 32;
    const unsigned short* Wb = W + col0 * DMODEL + kt * 32;
    {
      int cc  = tid;                 // 256 chunks for 64x32 A-tile
      int r   = cc >> 2;
      int ch  = cc & 3;
      int sch = ch ^ (r & 3);
      __builtin_amdgcn_global_load_lds(
          (const AS1 void*)(Ab + (size_t)r * DMODEL + sch * 8),
          (AS3 void*)(&As[buf][cc * 8]), 16, 0, 0);
    }
#pragma unroll
    for (int is = 0; is < 2; ++is) {
      int cc  = (wave * 2 + is) * 64 + lane;
      int r   = cc >> 2;
      int ch  = cc & 3;
      int sch = ch ^ (r & 3);
      __builtin_amdgcn_global_load_lds(
          (const AS1 void*)(Wb + (size_t)r * DMODEL + sch * 8),
          (AS3 void*)(&Ws[buf][cc * 8]), 16, 0, 0);
    }
  };

  stage(0, 0);
  __syncthreads();

  for (int kt = 0; kt < 32; ++kt) {
    const int cur = kt & 1;
    if (kt < 31) stage(cur ^ 1, kt + 1);

    bf16x8 af[2], bfr[4];
#pragma unroll
    for (int mi = 0; mi < 2; ++mi) {
      int r = wm * 32 + mi * 16 + l15;
      af[mi] = *(const bf16x8*)&As[cur][r * 32 + ((l4 ^ (r & 3)) << 3)];
    }
#pragma unroll
    for (int ni = 0; ni < 4; ++ni) {
      int r = wn * 64 + ni * 16 + l15;
      bfr[ni] = *(const bf16x8*)&Ws[cur][r * 32 + ((l4 ^ (r & 3)) << 3)];
    }
#pragma unroll
    for (int mi = 0; mi < 2; ++mi)
#pragma unroll
      for (int ni = 0; ni < 4; ++ni)
        acc[mi][ni] = __builtin_amdgcn_mfma_f32_16x16x32_bf16(af[mi], bfr[ni], acc[mi][ni], 0, 0, 0);

    __syncthreads();
  }

#pragma unroll
  for (int mi = 0; mi < 2; ++mi) {
#pragma unroll
    for (int ni = 0; ni < 4; ++ni) {
      const int col = (int)col0 + wn * 64 + ni * 16 + l15;
      const float bcol = bias[col];
#pragma unroll
      for (int i = 0; i < 4; ++i) {
        const size_t row = row0 + wm * 32 + mi * 16 + l4 * 4 + i;
        const size_t idx = row * DMODEL + col;
        out[idx] = resid[idx] + acc[mi][ni][i] + bcol;
      }
    }
  }
}

// ---------------------------------------------------------------- flash attention
// flat grid 1024; XCD-grouped; swapped QK^T; l via ones-column; defer-max;
// gate bias prefetched into registers (no LDS) -> 40960B LDS = 4 blocks/CU.
__global__ __launch_bounds__(256, 4)
void attn_kernel(const unsigned short* __restrict__ qb,
                 const unsigned short* __restrict__ kb,
                 const unsigned short* __restrict__ vt,
                 const float* __restrict__ lgb,
                 unsigned short* __restrict__ attn)
{
  __shared__ unsigned short Ks[2][64 * 64];
  __shared__ unsigned short Vs[2][64 * 64];
  __shared__ unsigned short Ps[4][16 * 64];

  const int tid  = threadIdx.x;
  const int wave = tid >> 6;
  const int lane = tid & 63;
  const int l15  = lane & 15;
  const int l4   = lane >> 4;

  const int bid  = blockIdx.x;
  const int xcd  = bid & 7;
  const int slot = bid >> 3;
  const int m_i  = slot & 15;
  const int grp  = slot >> 4;
  const int bh   = grp * 8 + xcd;
  const int b    = bh >> 4;
  const int h    = bh & 15;
  const int m0   = m_i * 64;

  const unsigned short* qg = qb + ((size_t)(b * MM + m0)) * DMODEL + h * DHEAD;
  const unsigned short* kg = kb + ((size_t)b * NN) * DMODEL + h * DHEAD;
  const unsigned short* vg = vt + ((size_t)(b * NHEAD + h)) * (DHEAD * (size_t)NN);
  const float* gg = lgb + (size_t)b * NN;

  bf16x8 qf0, qf1;
  {
    const unsigned short* qrow = qg + (size_t)(wave * 16 + l15) * DMODEL;
    qf0 = *(const bf16x8*)(qrow + l4 * 8);
    qf1 = *(const bf16x8*)(qrow + 32 + l4 * 8);
  }

  bf16x8 ones;
  {
    const short one = (l15 == 0) ? (short)0x3f80 : (short)0;
#pragma unroll
    for (int j = 0; j < 8; ++j) ones[j] = one;
  }

  auto stageKV = [&](int buf, int nt) {
    const int n0 = nt * 64;
#pragma unroll
    for (int is = 0; is < 2; ++is) {
      int cc = (wave * 2 + is) * 64 + lane;
      int r  = cc >> 3;
      int ch = cc & 7;
      __builtin_amdgcn_global_load_lds(
          (const AS1 void*)(kg + (size_t)(n0 + r) * DMODEL + ((ch ^ (r & 7)) << 3)),
          (AS3 void*)(&Ks[buf][cc * 8]), 16, 0, 0);
    }
#pragma unroll
    for (int is = 0; is < 2; ++is) {
      int cc = (wave * 2 + is) * 64 + lane;
      int r  = cc >> 3;
      int ch = cc & 7;
      __builtin_amdgcn_global_load_lds(
          (const AS1 void*)(vg + (size_t)r * NN + n0 + ((ch ^ (r & 7)) << 3)),
          (AS3 void*)(&Vs[buf][cc * 8]), 16, 0, 0);
    }
  };

  // gate prefetch (registers)
  f32x4 gc[4], gn[4];
#pragma unroll
  for (int ni = 0; ni < 4; ++ni)
    gc[ni] = *(const f32x4*)&gg[ni * 16 + l4 * 4];

  stageKV(0, 0);

  f32x4 ovec[5] = {};
  float mrow = -1e30f;
  unsigned short* Pw = &Ps[wave][0];
  const int pbase = l15 * 128;
  const int s7 = l15 & 7;

  for (int nt = 0; nt < NN / 64; ++nt) {
    const int cur = nt & 1;
    asm volatile("s_waitcnt vmcnt(0)" ::: "memory");
    __builtin_amdgcn_s_barrier();
    __builtin_amdgcn_sched_barrier(0);
    if (nt < NN / 64 - 1) {
      stageKV(cur ^ 1, nt + 1);
#pragma unroll
      for (int ni = 0; ni < 4; ++ni)
        gn[ni] = *(const f32x4*)&gg[(nt + 1) * 64 + ni * 16 + l4 * 4];
    }

    // S^T tile: s[ni][i] = S[m = l15][n = ni*16 + l4*4 + i]
    f32x4 s[4];
    __builtin_amdgcn_s_setprio(1);
#pragma unroll
    for (int ni = 0; ni < 4; ++ni) {
      const int r = ni * 16 + l15;
      const int c0 = l4 ^ (r & 7);
      bf16x8 kf0 = *(const bf16x8*)&Ks[cur][r * 64 + (c0 << 3)];
      bf16x8 kf1 = *(const bf16x8*)&Ks[cur][r * 64 + ((c0 ^ 4) << 3)];
      f32x4 z = {};
      z = __builtin_amdgcn_mfma_f32_16x16x32_bf16(kf0, qf0, z, 0, 0, 0);
      s[ni] = __builtin_amdgcn_mfma_f32_16x16x32_bf16(kf1, qf1, z, 0, 0, 0);
    }
    __builtin_amdgcn_s_setprio(0);

    // gate (log2-domain, from regs) + tile max
    float tmax = -1e30f;
#pragma unroll
    for (int ni = 0; ni < 4; ++ni) {
#pragma unroll
      for (int i = 0; i < 4; ++i)
        s[ni][i] = fmaf(gc[ni][i], LOG2E, s[ni][i]);
      tmax = fmaxf(tmax, fmaxf(fmaxf(s[ni][0], s[ni][1]), fmaxf(s[ni][2], s[ni][3])));
    }
    tmax = fmaxf(tmax, __shfl_xor(tmax, 16));
    tmax = fmaxf(tmax, __shfl_xor(tmax, 32));

    if (!__all(tmax <= mrow)) {
      const float mnew  = fmaxf(mrow, tmax);
      const float alpha = __builtin_amdgcn_exp2f(mrow - mnew);
      mrow = mnew;
      const int abase = l4 << 2;
#pragma unroll
      for (int i = 0; i < 4; ++i) {
        const float ai = __shfl(alpha, abase + i);
        ovec[0][i] *= ai; ovec[1][i] *= ai; ovec[2][i] *= ai;
        ovec[3][i] *= ai; ovec[4][i] *= ai;
      }
    }

    // p = exp2(s - m), pack bf16, write P (swizzled, wave-private)
#pragma unroll
    for (int ni = 0; ni < 4; ++ni) {
      union { unsigned short us[4]; uint2 u; } pk;
#pragma unroll
      for (int i = 0; i < 4; ++i)
        pk.us[i] = __builtin_bit_cast(unsigned short,
                     __float2bfloat16(__builtin_amdgcn_exp2f(s[ni][i] - mrow)));
      *(uint2*)((char*)Pw + pbase + (((ni * 4 + l4) ^ (s7 << 1)) << 3)) = pk.u;
    }
    asm volatile("s_waitcnt lgkmcnt(0)" ::: "memory");
    __builtin_amdgcn_sched_barrier(0);

    // O += P @ V ; l += P @ 1
    __builtin_amdgcn_s_setprio(1);
#pragma unroll
    for (int ks2 = 0; ks2 < 2; ++ks2) {
      const bf16x8 pf = *(const bf16x8*)((const char*)Pw + pbase + (((ks2 * 4 + l4) ^ s7) << 4));
#pragma unroll
      for (int di = 0; di < 4; ++di) {
        const int d = di * 16 + l15;
        const bf16x8 vf = *(const bf16x8*)&Vs[cur][d * 64 + (((ks2 * 4 + l4) ^ (d & 7)) << 3)];
        ovec[di] = __builtin_amdgcn_mfma_f32_16x16x32_bf16(pf, vf, ovec[di], 0, 0, 0);
      }
      ovec[4] = __builtin_amdgcn_mfma_f32_16x16x32_bf16(pf, ones, ovec[4], 0, 0, 0);
    }
    __builtin_amdgcn_s_setprio(0);

    if (nt < NN / 64 - 1) {
#pragma unroll
      for (int ni = 0; ni < 4; ++ni) gc[ni] = gn[ni];
    }
  }

  const int lsrc = lane & 48;
  float linv[4];
#pragma unroll
  for (int i = 0; i < 4; ++i)
    linv[i] = 1.0f / __shfl(ovec[4][i], lsrc);
#pragma unroll
  for (int di = 0; di < 4; ++di)
#pragma unroll
    for (int i = 0; i < 4; ++i) {
      const int row = m0 + wave * 16 + l4 * 4 + i;
      const int col = h * DHEAD + di * 16 + l15;
      attn[((size_t)(b * MM + row)) * DMODEL + col] =
        __builtin_bit_cast(unsigned short, __float2bfloat16(ovec[di][i] * linv[i]));
    }
}

// ---------------------------------------------------------------- LayerNorm
__global__ __launch_bounds__(256)
void ln_kernel(const float* __restrict__ x, const float* __restrict__ gamma,
               const float* __restrict__ beta, float* __restrict__ out)
{
  __shared__ float sh1[4], sh2[4];
  const int t = threadIdx.x;
  const size_t row = blockIdx.x;
  const float4 v = ((const float4*)(x + row * DMODEL))[t];

  float s = v.x + v.y + v.z + v.w;
#pragma unroll
  for (int m = 1; m < 64; m <<= 1) s += __shfl_xor(s, m);
  if ((t & 63) == 0) sh1[t >> 6] = s;
  __syncthreads();
  const float mu = (sh1[0] + sh1[1] + sh1[2] + sh1[3]) * (1.0f / DMODEL);

  const float dx = v.x - mu, dy = v.y - mu, dz = v.z - mu, dw = v.w - mu;
  float q = dx * dx + dy * dy + dz * dz + dw * dw;
#pragma unroll
  for (int m = 1; m < 64; m <<= 1) q += __shfl_xor(q, m);
  if ((t & 63) == 0) sh2[t >> 6] = q;
  __syncthreads();
  const float var = (sh2[0] + sh2[1] + sh2[2] + sh2[3]) * (1.0f / DMODEL);
  const float rstd = rsqrtf(var + 1e-5f);

  const float4 g  = ((const float4*)gamma)[t];
  const float4 be = ((const float4*)beta)[t];
  float4 o;
  o.x = dx * rstd * g.x + be.x;
  o.y = dy * rstd * g.y + be.y;
  o.z = dz * rstd * g.z + be.z;
  o.w = dw * rstd * g.w + be.w;
  ((float4*)(out + row * DMODEL))[t] = o;
}

// ---------------------------------------------------------------- launch
extern "C" void kernel_launch(void* const* d_in, const int* in_sizes, int n_in,
                              void* d_out, int out_size, void* d_ws, size_t ws_size,
                              hipStream_t stream)
{
  const float* Qf    = (const float*)d_in[0];
  const float* KVf   = (const float*)d_in[1];
  const float* lgb   = (const float*)d_in[2];
  const float* Wq    = (const float*)d_in[3];
  const float* bq    = (const float*)d_in[4];
  const float* Wk    = (const float*)d_in[5];
  const float* bk    = (const float*)d_in[6];
  const float* Wv    = (const float*)d_in[7];
  const float* bv    = (const float*)d_in[8];
  const float* Wo    = (const float*)d_in[9];
  const float* bo    = (const float*)d_in[10];
  const float* gamma = (const float*)d_in[11];
  const float* beta  = (const float*)d_in[12];
  float* out = (float*)d_out;

  char* ws = (char*)d_ws;
  unsigned short* Qbf   = (unsigned short*)(ws + 0);          // 8 MB; attnb aliases after Q dead
  unsigned short* attnb = Qbf;
  unsigned short* KVbf  = (unsigned short*)(ws + 8388608);    // 16 MB; xbuf aliases after KV dead
  float*          xbuf  = (float*)(ws + 8388608);
  unsigned short* Wqb = (unsigned short*)(ws + 25165824);
  unsigned short* Wkb = (unsigned short*)(ws + 27262976);
  unsigned short* Wvb = (unsigned short*)(ws + 29360128);
  unsigned short* Wob = (unsigned short*)(ws + 31457280);
  unsigned short* qbuf  = (unsigned short*)(ws + 33554432);   // 8 MB
  unsigned short* kbuf  = (unsigned short*)(ws + 41943040);   // 16 MB
  unsigned short* vtbuf = (unsigned short*)(ws + 58720256);   // 16 MB (V^T, written by qkv_gemm)

  dim3 blk(256);
  cast_all<<<16384, blk, 0, stream>>>(Qf, KVf, Wq, Wk, Wv, Wo,
                                      Qbf, KVbf, Wqb, Wkb, Wvb, Wob);

  qkv_gemm<<<1280, blk, 0, stream>>>(Qbf, KVbf, Wqb, Wkb, Wvb,
                                     bq, bk, bv, qbuf, kbuf, vtbuf);

  attn_kernel<<<1024, blk, 0, stream>>>(qbuf, kbuf, vtbuf, lgb, attnb);

  gemm_o<<<512, blk, 0, stream>>>(attnb, Wob, bo, Qf, xbuf);

  ln_kernel<<<4096, blk, 0, stream>>>(xbuf, gamma, beta, out);
}

// Round 6
// 171.485 us; speedup vs baseline: 1.6993x; 1.0439x over previous
//
#include <hip/hip_runtime.h>
#include <hip/hip_bf16.h>

#define DMODEL 1024
#define NHEAD  16
#define DHEAD  64
#define BB     4
#define MM     1024
#define NN     2048
#define LOG2E  1.4426950408889634f

typedef __attribute__((ext_vector_type(8))) short bf16x8;
typedef __attribute__((ext_vector_type(4))) float f32x4;

#define AS1 __attribute__((address_space(1)))
#define AS3 __attribute__((address_space(3)))

__device__ __forceinline__ unsigned short f2bf(float f) {
  unsigned int u = __builtin_bit_cast(unsigned int, f);
  unsigned int r = (u + 0x7fffu + ((u >> 16) & 1u)) >> 16;
  return (unsigned short)r;
}

// ---------------------------------------------------------------- fused cast f32 -> bf16
__global__ __launch_bounds__(256)
void cast_all(const float* __restrict__ Q, const float* __restrict__ KV,
              const float* __restrict__ W0, const float* __restrict__ W1,
              const float* __restrict__ W2, const float* __restrict__ W3,
              unsigned short* __restrict__ oQ, unsigned short* __restrict__ oKV,
              unsigned short* __restrict__ o0, unsigned short* __restrict__ o1,
              unsigned short* __restrict__ o2, unsigned short* __restrict__ o3)
{
  const int bid = blockIdx.x;
  const float* s; unsigned short* d; int i;
  if (bid < 4096)       { s = Q;  d = oQ;  i = bid * 256 + threadIdx.x; }
  else if (bid < 12288) { s = KV; d = oKV; i = (bid - 4096) * 256 + threadIdx.x; }
  else {
    const int w = (bid - 12288) >> 10;
    s = w == 0 ? W0 : w == 1 ? W1 : w == 2 ? W2 : W3;
    d = w == 0 ? o0 : w == 1 ? o1 : w == 2 ? o2 : o3;
    i = ((bid - 12288) & 1023) * 256 + threadIdx.x;
  }
  const float4 v = ((const float4*)s)[i];
  union { unsigned short us[4]; unsigned long long u64; } o;
  o.us[0] = f2bf(v.x); o.us[1] = f2bf(v.y); o.us[2] = f2bf(v.z); o.us[3] = f2bf(v.w);
  *(unsigned long long*)(d + (size_t)i * 4) = o.u64;
}

// ---------------------------------------------------------------- fused QKV GEMM
// flat grid 1280; XCD-slab mapping so A row-panels are co-XCD.
__global__ __launch_bounds__(256)
void qkv_gemm(const unsigned short* __restrict__ Qbf,
              const unsigned short* __restrict__ KVbf,
              const unsigned short* __restrict__ Wqb,
              const unsigned short* __restrict__ Wkb,
              const unsigned short* __restrict__ Wvb,
              const float* __restrict__ bq, const float* __restrict__ bk,
              const float* __restrict__ bv,
              unsigned short* __restrict__ qout,
              unsigned short* __restrict__ kout,
              unsigned short* __restrict__ vtout)
{
  __shared__ unsigned short As[2][128 * 32];
  __shared__ unsigned short Ws[2][128 * 32];

  const int bid = blockIdx.x;
  const unsigned short* A; const unsigned short* W; const float* bias;
  int mode, lb, nmb;
  if (bid < 256)      { A = Qbf;  W = Wqb; bias = bq; mode = 0; lb = bid;       nmb = 4; }
  else if (bid < 768) { A = KVbf; W = Wkb; bias = bk; mode = 1; lb = bid - 256; nmb = 8; }
  else                { A = KVbf; W = Wvb; bias = bv; mode = 2; lb = bid - 768; nmb = 8; }
  const int xcd = lb & 7;
  const int l   = lb >> 3;
  const int mb  = xcd * nmb + (l >> 3);
  const int nb  = l & 7;

  const int tid  = threadIdx.x;
  const int wave = tid >> 6;
  const int lane = tid & 63;
  const int l15  = lane & 15;
  const int l4   = lane >> 4;
  const int wm   = wave >> 1;
  const int wn   = wave & 1;
  const size_t row0 = (size_t)mb * 128;
  const size_t col0 = (size_t)nb * 128;

  f32x4 acc[4][4] = {};

  // hoisted staging pointers (advance 32 elems per K-step)
  const int cc0 = (wave * 2) * 64 + lane;
  const int cc1 = cc0 + 64;
  const int r0 = cc0 >> 2, sch0 = (cc0 & 3) ^ (r0 & 3);
  const int r1 = cc1 >> 2, sch1 = (cc1 & 3) ^ (r1 & 3);
  const unsigned short* ap0 = A + (row0 + r0) * DMODEL + sch0 * 8;
  const unsigned short* ap1 = A + (row0 + r1) * DMODEL + sch1 * 8;
  const unsigned short* wp0 = W + (col0 + r0) * DMODEL + sch0 * 8;
  const unsigned short* wp1 = W + (col0 + r1) * DMODEL + sch1 * 8;

  auto stage = [&](int buf) {
    __builtin_amdgcn_global_load_lds((const AS1 void*)ap0, (AS3 void*)(&As[buf][cc0 * 8]), 16, 0, 0);
    __builtin_amdgcn_global_load_lds((const AS1 void*)ap1, (AS3 void*)(&As[buf][cc1 * 8]), 16, 0, 0);
    __builtin_amdgcn_global_load_lds((const AS1 void*)wp0, (AS3 void*)(&Ws[buf][cc0 * 8]), 16, 0, 0);
    __builtin_amdgcn_global_load_lds((const AS1 void*)wp1, (AS3 void*)(&Ws[buf][cc1 * 8]), 16, 0, 0);
    ap0 += 32; ap1 += 32; wp0 += 32; wp1 += 32;
  };

  stage(0);
  __syncthreads();

  for (int kt = 0; kt < 32; ++kt) {
    const int cur = kt & 1;
    if (kt < 31) stage(cur ^ 1);

    bf16x8 af[4], bfr[4];
#pragma unroll
    for (int mi = 0; mi < 4; ++mi) {
      int r = wm * 64 + mi * 16 + l15;
      af[mi] = *(const bf16x8*)&As[cur][r * 32 + ((l4 ^ (r & 3)) << 3)];
    }
#pragma unroll
    for (int ni = 0; ni < 4; ++ni) {
      int r = wn * 64 + ni * 16 + l15;
      bfr[ni] = *(const bf16x8*)&Ws[cur][r * 32 + ((l4 ^ (r & 3)) << 3)];
    }
#pragma unroll
    for (int mi = 0; mi < 4; ++mi)
#pragma unroll
      for (int ni = 0; ni < 4; ++ni)
        acc[mi][ni] = __builtin_amdgcn_mfma_f32_16x16x32_bf16(af[mi], bfr[ni], acc[mi][ni], 0, 0, 0);

    __syncthreads();
  }

#pragma unroll
  for (int mi = 0; mi < 4; ++mi) {
#pragma unroll
    for (int ni = 0; ni < 4; ++ni) {
      const int col = (int)col0 + wn * 64 + ni * 16 + l15;
      const float bcol = bias[col];
      if (mode == 2) {
        const int row = (int)row0 + wm * 64 + mi * 16 + l4 * 4;
        const int b = row >> 11, n = row & 2047;
        const int h = col >> 6, d = col & 63;
        union { unsigned short us[4]; uint2 u; } pk;
#pragma unroll
        for (int i = 0; i < 4; ++i)
          pk.us[i] = __builtin_bit_cast(unsigned short, __float2bfloat16(acc[mi][ni][i] + bcol));
        *(uint2*)(vtout + (((size_t)(b * 16 + h) * 64 + d) << 11) + n) = pk.u;
      } else {
#pragma unroll
        for (int i = 0; i < 4; ++i) {
          const size_t row = row0 + wm * 64 + mi * 16 + l4 * 4 + i;
          float v = acc[mi][ni][i] + bcol;
          if (mode == 0) v *= (0.125f * LOG2E);
          (mode == 0 ? qout : kout)[row * DMODEL + col] =
            __builtin_bit_cast(unsigned short, __float2bfloat16(v));
        }
      }
    }
  }
}

// ---------------------------------------------------------------- o-proj GEMM (64x128 tile)
__global__ __launch_bounds__(256)
void gemm_o(const unsigned short* __restrict__ A,
            const unsigned short* __restrict__ W,
            const float* __restrict__ bias,
            const float* __restrict__ resid,
            float* __restrict__ out)
{
  __shared__ unsigned short As[2][64 * 32];
  __shared__ unsigned short Ws[2][128 * 32];

  const int bid = blockIdx.x;
  const int xcd = bid & 7;
  const int l   = bid >> 3;
  const int mb  = xcd * 8 + (l >> 3);
  const int nb  = l & 7;

  const int tid  = threadIdx.x;
  const int wave = tid >> 6;
  const int lane = tid & 63;
  const int l15  = lane & 15;
  const int l4   = lane >> 4;
  const int wm   = wave >> 1;
  const int wn   = wave & 1;
  const size_t row0 = (size_t)mb * 64;
  const size_t col0 = (size_t)nb * 128;

  f32x4 acc[2][4] = {};

  const int ra = tid >> 2, scha = (tid & 3) ^ (ra & 3);
  const int cc0 = (wave * 2) * 64 + lane;
  const int cc1 = cc0 + 64;
  const int r0 = cc0 >> 2, sch0 = (cc0 & 3) ^ (r0 & 3);
  const int r1 = cc1 >> 2, sch1 = (cc1 & 3) ^ (r1 & 3);
  const unsigned short* ap  = A + (row0 + ra) * DMODEL + scha * 8;
  const unsigned short* wp0 = W + (col0 + r0) * DMODEL + sch0 * 8;
  const unsigned short* wp1 = W + (col0 + r1) * DMODEL + sch1 * 8;

  auto stage = [&](int buf) {
    __builtin_amdgcn_global_load_lds((const AS1 void*)ap,  (AS3 void*)(&As[buf][tid * 8]), 16, 0, 0);
    __builtin_amdgcn_global_load_lds((const AS1 void*)wp0, (AS3 void*)(&Ws[buf][cc0 * 8]), 16, 0, 0);
    __builtin_amdgcn_global_load_lds((const AS1 void*)wp1, (AS3 void*)(&Ws[buf][cc1 * 8]), 16, 0, 0);
    ap += 32; wp0 += 32; wp1 += 32;
  };

  stage(0);
  __syncthreads();

  for (int kt = 0; kt < 32; ++kt) {
    const int cur = kt & 1;
    if (kt < 31) stage(cur ^ 1);

    bf16x8 af[2], bfr[4];
#pragma unroll
    for (int mi = 0; mi < 2; ++mi) {
      int r = wm * 32 + mi * 16 + l15;
      af[mi] = *(const bf16x8*)&As[cur][r * 32 + ((l4 ^ (r & 3)) << 3)];
    }
#pragma unroll
    for (int ni = 0; ni < 4; ++ni) {
      int r = wn * 64 + ni * 16 + l15;
      bfr[ni] = *(const bf16x8*)&Ws[cur][r * 32 + ((l4 ^ (r & 3)) << 3)];
    }
#pragma unroll
    for (int mi = 0; mi < 2; ++mi)
#pragma unroll
      for (int ni = 0; ni < 4; ++ni)
        acc[mi][ni] = __builtin_amdgcn_mfma_f32_16x16x32_bf16(af[mi], bfr[ni], acc[mi][ni], 0, 0, 0);

    __syncthreads();
  }

#pragma unroll
  for (int mi = 0; mi < 2; ++mi) {
#pragma unroll
    for (int ni = 0; ni < 4; ++ni) {
      const int col = (int)col0 + wn * 64 + ni * 16 + l15;
      const float bcol = bias[col];
#pragma unroll
      for (int i = 0; i < 4; ++i) {
        const size_t row = row0 + wm * 32 + mi * 16 + l4 * 4 + i;
        const size_t idx = row * DMODEL + col;
        out[idx] = resid[idx] + acc[mi][ni][i] + bcol;
      }
    }
  }
}

// ---------------------------------------------------------------- flash attention
// grid 512 x 512 threads (8 waves); staging shared by 8 waves; hoisted pointers.
// XCD-grouped (8 m-blocks of one (b,h) per XCD); swapped QK^T; l via ones-column;
// defer-max; gate staged to LDS by wave 0.
__global__ __launch_bounds__(512, 4)
void attn_kernel(const unsigned short* __restrict__ qb,
                 const unsigned short* __restrict__ kb,
                 const unsigned short* __restrict__ vt,
                 const float* __restrict__ lgb,
                 unsigned short* __restrict__ attn)
{
  __shared__ unsigned short Ks[2][64 * 64];
  __shared__ unsigned short Vs[2][64 * 64];
  __shared__ float Gs[2][64];
  __shared__ unsigned short Ps[8][16 * 64];

  const int tid  = threadIdx.x;
  const int wave = tid >> 6;
  const int lane = tid & 63;
  const int l15  = lane & 15;
  const int l4   = lane >> 4;

  const int bid  = blockIdx.x;
  const int xcd  = bid & 7;
  const int slot = bid >> 3;
  const int m_i  = slot & 7;
  const int grp  = slot >> 3;
  const int bh   = grp * 8 + xcd;
  const int b    = bh >> 4;
  const int h    = bh & 15;
  const int m0   = m_i * 128;

  const unsigned short* qg = qb + ((size_t)(b * MM + m0)) * DMODEL + h * DHEAD;
  const unsigned short* kg = kb + ((size_t)b * NN) * DMODEL + h * DHEAD;
  const unsigned short* vg = vt + ((size_t)(b * NHEAD + h)) * (DHEAD * (size_t)NN);

  // Q B-fragments (row m = wave*16 + l15, d-chunk l4 / l4+4)
  bf16x8 qf0, qf1;
  {
    const unsigned short* qrow = qg + (size_t)(wave * 16 + l15) * DMODEL;
    qf0 = *(const bf16x8*)(qrow + l4 * 8);
    qf1 = *(const bf16x8*)(qrow + 32 + l4 * 8);
  }

  bf16x8 ones;
  {
    const short one = (l15 == 0) ? (short)0x3f80 : (short)0;
#pragma unroll
    for (int j = 0; j < 8; ++j) ones[j] = one;
  }

  // hoisted staging pointers: 512 threads cover one 64x64 tile each for K and V
  const int sr = tid >> 3;            // row 0..63
  const int sc = (tid & 7) ^ (sr & 7);
  const unsigned short* kp = kg + (size_t)sr * DMODEL + (sc << 3);  // +64 rows/tile
  const unsigned short* vp = vg + (size_t)sr * NN + (sc << 3);      // +64 cols/tile
  const float* gp = lgb + (size_t)b * NN + lane;                    // wave 0 only

  auto stage = [&](int buf) {
    if (wave == 0)
      __builtin_amdgcn_global_load_lds((const AS1 void*)gp, (AS3 void*)(&Gs[buf][lane]), 4, 0, 0);
    __builtin_amdgcn_global_load_lds((const AS1 void*)kp, (AS3 void*)(&Ks[buf][tid * 8]), 16, 0, 0);
    __builtin_amdgcn_global_load_lds((const AS1 void*)vp, (AS3 void*)(&Vs[buf][tid * 8]), 16, 0, 0);
    kp += 64 * DMODEL; vp += 64; gp += 64;
  };

  stage(0);

  f32x4 ovec[5] = {};
  float mrow = -1e30f;
  unsigned short* Pw = &Ps[wave][0];
  const int pbase = l15 * 128;
  const int s7 = l15 & 7;

  for (int nt = 0; nt < NN / 64; ++nt) {
    const int cur = nt & 1;
    asm volatile("s_waitcnt vmcnt(0)" ::: "memory");
    __builtin_amdgcn_sched_barrier(0);
    __builtin_amdgcn_s_barrier();
    __builtin_amdgcn_sched_barrier(0);
    if (nt < NN / 64 - 1) stage(cur ^ 1);

    // S^T tile: s[ni][i] = S[m = l15][n = ni*16 + l4*4 + i]
    f32x4 s[4];
    __builtin_amdgcn_s_setprio(1);
#pragma unroll
    for (int ni = 0; ni < 4; ++ni) {
      const int r = ni * 16 + l15;
      const int c0 = l4 ^ (r & 7);
      bf16x8 kf0 = *(const bf16x8*)&Ks[cur][r * 64 + (c0 << 3)];
      bf16x8 kf1 = *(const bf16x8*)&Ks[cur][r * 64 + ((c0 ^ 4) << 3)];
      f32x4 z = {};
      z = __builtin_amdgcn_mfma_f32_16x16x32_bf16(kf0, qf0, z, 0, 0, 0);
      s[ni] = __builtin_amdgcn_mfma_f32_16x16x32_bf16(kf1, qf1, z, 0, 0, 0);
    }
    __builtin_amdgcn_s_setprio(0);

    // gate (log2-domain, from LDS) + tile max
    float tmax = -1e30f;
#pragma unroll
    for (int ni = 0; ni < 4; ++ni) {
      const float4 g = *(const float4*)&Gs[cur][ni * 16 + l4 * 4];
      s[ni][0] = fmaf(g.x, LOG2E, s[ni][0]);
      s[ni][1] = fmaf(g.y, LOG2E, s[ni][1]);
      s[ni][2] = fmaf(g.z, LOG2E, s[ni][2]);
      s[ni][3] = fmaf(g.w, LOG2E, s[ni][3]);
      tmax = fmaxf(tmax, fmaxf(fmaxf(s[ni][0], s[ni][1]), fmaxf(s[ni][2], s[ni][3])));
    }
    tmax = fmaxf(tmax, __shfl_xor(tmax, 16));
    tmax = fmaxf(tmax, __shfl_xor(tmax, 32));

    if (!__all(tmax <= mrow)) {
      const float mnew  = fmaxf(mrow, tmax);
      const float alpha = __builtin_amdgcn_exp2f(mrow - mnew);
      mrow = mnew;
      const int abase = l4 << 2;
#pragma unroll
      for (int i = 0; i < 4; ++i) {
        const float ai = __shfl(alpha, abase + i);
        ovec[0][i] *= ai; ovec[1][i] *= ai; ovec[2][i] *= ai;
        ovec[3][i] *= ai; ovec[4][i] *= ai;
      }
    }

    // p = exp2(s - m), pack bf16, write P (swizzled, wave-private)
#pragma unroll
    for (int ni = 0; ni < 4; ++ni) {
      union { unsigned short us[4]; uint2 u; } pk;
#pragma unroll
      for (int i = 0; i < 4; ++i)
        pk.us[i] = __builtin_bit_cast(unsigned short,
                     __float2bfloat16(__builtin_amdgcn_exp2f(s[ni][i] - mrow)));
      *(uint2*)((char*)Pw + pbase + (((ni * 4 + l4) ^ (s7 << 1)) << 3)) = pk.u;
    }
    asm volatile("s_waitcnt lgkmcnt(0)" ::: "memory");
    __builtin_amdgcn_sched_barrier(0);

    // O += P @ V ; l += P @ 1
    __builtin_amdgcn_s_setprio(1);
#pragma unroll
    for (int ks2 = 0; ks2 < 2; ++ks2) {
      const bf16x8 pf = *(const bf16x8*)((const char*)Pw + pbase + (((ks2 * 4 + l4) ^ s7) << 4));
#pragma unroll
      for (int di = 0; di < 4; ++di) {
        const int d = di * 16 + l15;
        const bf16x8 vf = *(const bf16x8*)&Vs[cur][d * 64 + (((ks2 * 4 + l4) ^ (d & 7)) << 3)];
        ovec[di] = __builtin_amdgcn_mfma_f32_16x16x32_bf16(pf, vf, ovec[di], 0, 0, 0);
      }
      ovec[4] = __builtin_amdgcn_mfma_f32_16x16x32_bf16(pf, ones, ovec[4], 0, 0, 0);
    }
    __builtin_amdgcn_s_setprio(0);
  }

  const int lsrc = lane & 48;
  float linv[4];
#pragma unroll
  for (int i = 0; i < 4; ++i)
    linv[i] = 1.0f / __shfl(ovec[4][i], lsrc);
#pragma unroll
  for (int di = 0; di < 4; ++di)
#pragma unroll
    for (int i = 0; i < 4; ++i) {
      const int row = m0 + wave * 16 + l4 * 4 + i;
      const int col = h * DHEAD + di * 16 + l15;
      attn[((size_t)(b * MM + row)) * DMODEL + col] =
        __builtin_bit_cast(unsigned short, __float2bfloat16(ovec[di][i] * linv[i]));
    }
}

// ---------------------------------------------------------------- LayerNorm
__global__ __launch_bounds__(256)
void ln_kernel(const float* __restrict__ x, const float* __restrict__ gamma,
               const float* __restrict__ beta, float* __restrict__ out)
{
  __shared__ float sh1[4], sh2[4];
  const int t = threadIdx.x;
  const size_t row = blockIdx.x;
  const float4 v = ((const float4*)(x + row * DMODEL))[t];

  float s = v.x + v.y + v.z + v.w;
#pragma unroll
  for (int m = 1; m < 64; m <<= 1) s += __shfl_xor(s, m);
  if ((t & 63) == 0) sh1[t >> 6] = s;
  __syncthreads();
  const float mu = (sh1[0] + sh1[1] + sh1[2] + sh1[3]) * (1.0f / DMODEL);

  const float dx = v.x - mu, dy = v.y - mu, dz = v.z - mu, dw = v.w - mu;
  float q = dx * dx + dy * dy + dz * dz + dw * dw;
#pragma unroll
  for (int m = 1; m < 64; m <<= 1) q += __shfl_xor(q, m);
  if ((t & 63) == 0) sh2[t >> 6] = q;
  __syncthreads();
  const float var = (sh2[0] + sh2[1] + sh2[2] + sh2[3]) * (1.0f / DMODEL);
  const float rstd = rsqrtf(var + 1e-5f);

  const float4 g  = ((const float4*)gamma)[t];
  const float4 be = ((const float4*)beta)[t];
  float4 o;
  o.x = dx * rstd * g.x + be.x;
  o.y = dy * rstd * g.y + be.y;
  o.z = dz * rstd * g.z + be.z;
  o.w = dw * rstd * g.w + be.w;
  ((float4*)(out + row * DMODEL))[t] = o;
}

// ---------------------------------------------------------------- launch
extern "C" void kernel_launch(void* const* d_in, const int* in_sizes, int n_in,
                              void* d_out, int out_size, void* d_ws, size_t ws_size,
                              hipStream_t stream)
{
  const float* Qf    = (const float*)d_in[0];
  const float* KVf   = (const float*)d_in[1];
  const float* lgb   = (const float*)d_in[2];
  const float* Wq    = (const float*)d_in[3];
  const float* bq    = (const float*)d_in[4];
  const float* Wk    = (const float*)d_in[5];
  const float* bk    = (const float*)d_in[6];
  const float* Wv    = (const float*)d_in[7];
  const float* bv    = (const float*)d_in[8];
  const float* Wo    = (const float*)d_in[9];
  const float* bo    = (const float*)d_in[10];
  const float* gamma = (const float*)d_in[11];
  const float* beta  = (const float*)d_in[12];
  float* out = (float*)d_out;

  char* ws = (char*)d_ws;
  unsigned short* Qbf   = (unsigned short*)(ws + 0);          // 8 MB; attnb aliases after Q dead
  unsigned short* attnb = Qbf;
  unsigned short* KVbf  = (unsigned short*)(ws + 8388608);    // 16 MB; xbuf aliases after KV dead
  float*          xbuf  = (float*)(ws + 8388608);
  unsigned short* Wqb = (unsigned short*)(ws + 25165824);
  unsigned short* Wkb = (unsigned short*)(ws + 27262976);
  unsigned short* Wvb = (unsigned short*)(ws + 29360128);
  unsigned short* Wob = (unsigned short*)(ws + 31457280);
  unsigned short* qbuf  = (unsigned short*)(ws + 33554432);   // 8 MB
  unsigned short* kbuf  = (unsigned short*)(ws + 41943040);   // 16 MB
  unsigned short* vtbuf = (unsigned short*)(ws + 58720256);   // 16 MB (V^T)

  cast_all<<<16384, dim3(256), 0, stream>>>(Qf, KVf, Wq, Wk, Wv, Wo,
                                            Qbf, KVbf, Wqb, Wkb, Wvb, Wob);

  qkv_gemm<<<1280, dim3(256), 0, stream>>>(Qbf, KVbf, Wqb, Wkb, Wvb,
                                           bq, bk, bv, qbuf, kbuf, vtbuf);

  attn_kernel<<<512, dim3(512), 0, stream>>>(qbuf, kbuf, vtbuf, lgb, attnb);

  gemm_o<<<512, dim3(256), 0, stream>>>(attnb, Wob, bo, Qf, xbuf);

  ln_kernel<<<4096, dim3(256), 0, stream>>>(xbuf, gamma, beta, out);
}

// Round 7
// 169.460 us; speedup vs baseline: 1.7196x; 1.0120x over previous
//
#include <hip/hip_runtime.h>
#include <hip/hip_bf16.h>

#define DMODEL 1024
#define NHEAD  16
#define DHEAD  64
#define BB     4
#define MM     1024
#define NN     2048
#define LOG2E  1.4426950408889634f

typedef __attribute__((ext_vector_type(8))) short bf16x8;
typedef __attribute__((ext_vector_type(4))) float f32x4;

#define AS1 __attribute__((address_space(1)))
#define AS3 __attribute__((address_space(3)))

__device__ __forceinline__ unsigned short f2bf(float f) {
  unsigned int u = __builtin_bit_cast(unsigned int, f);
  unsigned int r = (u + 0x7fffu + ((u >> 16) & 1u)) >> 16;
  return (unsigned short)r;
}

// ---------------------------------------------------------------- fused cast f32 -> bf16
__global__ __launch_bounds__(256)
void cast_all(const float* __restrict__ Q, const float* __restrict__ KV,
              const float* __restrict__ W0, const float* __restrict__ W1,
              const float* __restrict__ W2, const float* __restrict__ W3,
              unsigned short* __restrict__ oQ, unsigned short* __restrict__ oKV,
              unsigned short* __restrict__ o0, unsigned short* __restrict__ o1,
              unsigned short* __restrict__ o2, unsigned short* __restrict__ o3)
{
  const int bid = blockIdx.x;
  const float* s; unsigned short* d; int i;
  if (bid < 4096)       { s = Q;  d = oQ;  i = bid * 256 + threadIdx.x; }
  else if (bid < 12288) { s = KV; d = oKV; i = (bid - 4096) * 256 + threadIdx.x; }
  else {
    const int w = (bid - 12288) >> 10;
    s = w == 0 ? W0 : w == 1 ? W1 : w == 2 ? W2 : W3;
    d = w == 0 ? o0 : w == 1 ? o1 : w == 2 ? o2 : o3;
    i = ((bid - 12288) & 1023) * 256 + threadIdx.x;
  }
  const float4 v = ((const float4*)s)[i];
  union { unsigned short us[4]; unsigned long long u64; } o;
  o.us[0] = f2bf(v.x); o.us[1] = f2bf(v.y); o.us[2] = f2bf(v.z); o.us[3] = f2bf(v.w);
  *(unsigned long long*)(d + (size_t)i * 4) = o.u64;
}

// ---------------------------------------------------------------- fused QKV GEMM
// flat grid 1280; XCD-slab mapping; counted-vmcnt 2-barrier K-loop (T4).
__global__ __launch_bounds__(256)
void qkv_gemm(const unsigned short* __restrict__ Qbf,
              const unsigned short* __restrict__ KVbf,
              const unsigned short* __restrict__ Wqb,
              const unsigned short* __restrict__ Wkb,
              const unsigned short* __restrict__ Wvb,
              const float* __restrict__ bq, const float* __restrict__ bk,
              const float* __restrict__ bv,
              unsigned short* __restrict__ qout,
              unsigned short* __restrict__ kout,
              unsigned short* __restrict__ vtout)
{
  __shared__ unsigned short As[2][128 * 32];
  __shared__ unsigned short Ws[2][128 * 32];

  const int bid = blockIdx.x;
  const unsigned short* A; const unsigned short* W; const float* bias;
  int mode, lb, nmb;
  if (bid < 256)      { A = Qbf;  W = Wqb; bias = bq; mode = 0; lb = bid;       nmb = 4; }
  else if (bid < 768) { A = KVbf; W = Wkb; bias = bk; mode = 1; lb = bid - 256; nmb = 8; }
  else                { A = KVbf; W = Wvb; bias = bv; mode = 2; lb = bid - 768; nmb = 8; }
  const int xcd = lb & 7;
  const int l   = lb >> 3;
  const int mb  = xcd * nmb + (l >> 3);
  const int nb  = l & 7;

  const int tid  = threadIdx.x;
  const int wave = tid >> 6;
  const int lane = tid & 63;
  const int l15  = lane & 15;
  const int l4   = lane >> 4;
  const int wm   = wave >> 1;
  const int wn   = wave & 1;
  const size_t row0 = (size_t)mb * 128;
  const size_t col0 = (size_t)nb * 128;

  f32x4 acc[4][4] = {};

  const int cc0 = (wave * 2) * 64 + lane;
  const int cc1 = cc0 + 64;
  const int r0 = cc0 >> 2, sch0 = (cc0 & 3) ^ (r0 & 3);
  const int r1 = cc1 >> 2, sch1 = (cc1 & 3) ^ (r1 & 3);
  const unsigned short* ap0 = A + (row0 + r0) * DMODEL + sch0 * 8;
  const unsigned short* ap1 = A + (row0 + r1) * DMODEL + sch1 * 8;
  const unsigned short* wp0 = W + (col0 + r0) * DMODEL + sch0 * 8;
  const unsigned short* wp1 = W + (col0 + r1) * DMODEL + sch1 * 8;

  auto stage = [&](int buf) {
    __builtin_amdgcn_global_load_lds((const AS1 void*)ap0, (AS3 void*)(&As[buf][cc0 * 8]), 16, 0, 0);
    __builtin_amdgcn_global_load_lds((const AS1 void*)ap1, (AS3 void*)(&As[buf][cc1 * 8]), 16, 0, 0);
    __builtin_amdgcn_global_load_lds((const AS1 void*)wp0, (AS3 void*)(&Ws[buf][cc0 * 8]), 16, 0, 0);
    __builtin_amdgcn_global_load_lds((const AS1 void*)wp1, (AS3 void*)(&Ws[buf][cc1 * 8]), 16, 0, 0);
    ap0 += 32; ap1 += 32; wp0 += 32; wp1 += 32;
  };

  stage(0);

  for (int kt = 0; kt < 32; ++kt) {
    const int cur = kt & 1;
    // issue next tile, then wait ONLY the current tile's 4 loads (T4 counted vmcnt)
    if (kt < 31) {
      stage(cur ^ 1);
      asm volatile("s_waitcnt vmcnt(4)" ::: "memory");
    } else {
      asm volatile("s_waitcnt vmcnt(0)" ::: "memory");
    }
    __builtin_amdgcn_sched_barrier(0);
    __builtin_amdgcn_s_barrier();          // A: cur fully staged (all waves)
    __builtin_amdgcn_sched_barrier(0);

    bf16x8 af[4], bfr[4];
#pragma unroll
    for (int mi = 0; mi < 4; ++mi) {
      int r = wm * 64 + mi * 16 + l15;
      af[mi] = *(const bf16x8*)&As[cur][r * 32 + ((l4 ^ (r & 3)) << 3)];
    }
#pragma unroll
    for (int ni = 0; ni < 4; ++ni) {
      int r = wn * 64 + ni * 16 + l15;
      bfr[ni] = *(const bf16x8*)&Ws[cur][r * 32 + ((l4 ^ (r & 3)) << 3)];
    }
    __builtin_amdgcn_s_setprio(1);
#pragma unroll
    for (int mi = 0; mi < 4; ++mi)
#pragma unroll
      for (int ni = 0; ni < 4; ++ni)
        acc[mi][ni] = __builtin_amdgcn_mfma_f32_16x16x32_bf16(af[mi], bfr[ni], acc[mi][ni], 0, 0, 0);
    __builtin_amdgcn_s_setprio(0);

    asm volatile("s_waitcnt lgkmcnt(0)" ::: "memory");
    __builtin_amdgcn_sched_barrier(0);
    __builtin_amdgcn_s_barrier();          // B: reads done -> next stage may overwrite
    __builtin_amdgcn_sched_barrier(0);
  }

#pragma unroll
  for (int mi = 0; mi < 4; ++mi) {
#pragma unroll
    for (int ni = 0; ni < 4; ++ni) {
      const int col = (int)col0 + wn * 64 + ni * 16 + l15;
      const float bcol = bias[col];
      if (mode == 2) {
        const int row = (int)row0 + wm * 64 + mi * 16 + l4 * 4;
        const int b = row >> 11, n = row & 2047;
        const int h = col >> 6, d = col & 63;
        union { unsigned short us[4]; uint2 u; } pk;
#pragma unroll
        for (int i = 0; i < 4; ++i)
          pk.us[i] = __builtin_bit_cast(unsigned short, __float2bfloat16(acc[mi][ni][i] + bcol));
        *(uint2*)(vtout + (((size_t)(b * 16 + h) * 64 + d) << 11) + n) = pk.u;
      } else {
#pragma unroll
        for (int i = 0; i < 4; ++i) {
          const size_t row = row0 + wm * 64 + mi * 16 + l4 * 4 + i;
          float v = acc[mi][ni][i] + bcol;
          if (mode == 0) v *= (0.125f * LOG2E);
          (mode == 0 ? qout : kout)[row * DMODEL + col] =
            __builtin_bit_cast(unsigned short, __float2bfloat16(v));
        }
      }
    }
  }
}

// ---------------------------------------------------------------- o-proj GEMM (64x128 tile)
__global__ __launch_bounds__(256)
void gemm_o(const unsigned short* __restrict__ A,
            const unsigned short* __restrict__ W,
            const float* __restrict__ bias,
            const float* __restrict__ resid,
            float* __restrict__ out)
{
  __shared__ unsigned short As[2][64 * 32];
  __shared__ unsigned short Ws[2][128 * 32];

  const int bid = blockIdx.x;
  const int xcd = bid & 7;
  const int l   = bid >> 3;
  const int mb  = xcd * 8 + (l >> 3);
  const int nb  = l & 7;

  const int tid  = threadIdx.x;
  const int wave = tid >> 6;
  const int lane = tid & 63;
  const int l15  = lane & 15;
  const int l4   = lane >> 4;
  const int wm   = wave >> 1;
  const int wn   = wave & 1;
  const size_t row0 = (size_t)mb * 64;
  const size_t col0 = (size_t)nb * 128;

  f32x4 acc[2][4] = {};

  const int ra = tid >> 2, scha = (tid & 3) ^ (ra & 3);
  const int cc0 = (wave * 2) * 64 + lane;
  const int cc1 = cc0 + 64;
  const int r0 = cc0 >> 2, sch0 = (cc0 & 3) ^ (r0 & 3);
  const int r1 = cc1 >> 2, sch1 = (cc1 & 3) ^ (r1 & 3);
  const unsigned short* ap  = A + (row0 + ra) * DMODEL + scha * 8;
  const unsigned short* wp0 = W + (col0 + r0) * DMODEL + sch0 * 8;
  const unsigned short* wp1 = W + (col0 + r1) * DMODEL + sch1 * 8;

  auto stage = [&](int buf) {
    __builtin_amdgcn_global_load_lds((const AS1 void*)ap,  (AS3 void*)(&As[buf][tid * 8]), 16, 0, 0);
    __builtin_amdgcn_global_load_lds((const AS1 void*)wp0, (AS3 void*)(&Ws[buf][cc0 * 8]), 16, 0, 0);
    __builtin_amdgcn_global_load_lds((const AS1 void*)wp1, (AS3 void*)(&Ws[buf][cc1 * 8]), 16, 0, 0);
    ap += 32; wp0 += 32; wp1 += 32;
  };

  stage(0);

  for (int kt = 0; kt < 32; ++kt) {
    const int cur = kt & 1;
    if (kt < 31) {
      stage(cur ^ 1);
      asm volatile("s_waitcnt vmcnt(3)" ::: "memory");
    } else {
      asm volatile("s_waitcnt vmcnt(0)" ::: "memory");
    }
    __builtin_amdgcn_sched_barrier(0);
    __builtin_amdgcn_s_barrier();
    __builtin_amdgcn_sched_barrier(0);

    bf16x8 af[2], bfr[4];
#pragma unroll
    for (int mi = 0; mi < 2; ++mi) {
      int r = wm * 32 + mi * 16 + l15;
      af[mi] = *(const bf16x8*)&As[cur][r * 32 + ((l4 ^ (r & 3)) << 3)];
    }
#pragma unroll
    for (int ni = 0; ni < 4; ++ni) {
      int r = wn * 64 + ni * 16 + l15;
      bfr[ni] = *(const bf16x8*)&Ws[cur][r * 32 + ((l4 ^ (r & 3)) << 3)];
    }
    __builtin_amdgcn_s_setprio(1);
#pragma unroll
    for (int mi = 0; mi < 2; ++mi)
#pragma unroll
      for (int ni = 0; ni < 4; ++ni)
        acc[mi][ni] = __builtin_amdgcn_mfma_f32_16x16x32_bf16(af[mi], bfr[ni], acc[mi][ni], 0, 0, 0);
    __builtin_amdgcn_s_setprio(0);

    asm volatile("s_waitcnt lgkmcnt(0)" ::: "memory");
    __builtin_amdgcn_sched_barrier(0);
    __builtin_amdgcn_s_barrier();
    __builtin_amdgcn_sched_barrier(0);
  }

#pragma unroll
  for (int mi = 0; mi < 2; ++mi) {
#pragma unroll
    for (int ni = 0; ni < 4; ++ni) {
      const int col = (int)col0 + wn * 64 + ni * 16 + l15;
      const float bcol = bias[col];
#pragma unroll
      for (int i = 0; i < 4; ++i) {
        const size_t row = row0 + wm * 32 + mi * 16 + l4 * 4 + i;
        const size_t idx = row * DMODEL + col;
        out[idx] = resid[idx] + acc[mi][ni][i] + bcol;
      }
    }
  }
}

// ---------------------------------------------------------------- flash attention
// grid 512 x 512 threads (8 waves); staging shared by 8 waves; hoisted pointers.
__global__ __launch_bounds__(512, 4)
void attn_kernel(const unsigned short* __restrict__ qb,
                 const unsigned short* __restrict__ kb,
                 const unsigned short* __restrict__ vt,
                 const float* __restrict__ lgb,
                 unsigned short* __restrict__ attn)
{
  __shared__ unsigned short Ks[2][64 * 64];
  __shared__ unsigned short Vs[2][64 * 64];
  __shared__ float Gs[2][64];
  __shared__ unsigned short Ps[8][16 * 64];

  const int tid  = threadIdx.x;
  const int wave = tid >> 6;
  const int lane = tid & 63;
  const int l15  = lane & 15;
  const int l4   = lane >> 4;

  const int bid  = blockIdx.x;
  const int xcd  = bid & 7;
  const int slot = bid >> 3;
  const int m_i  = slot & 7;
  const int grp  = slot >> 3;
  const int bh   = grp * 8 + xcd;
  const int b    = bh >> 4;
  const int h    = bh & 15;
  const int m0   = m_i * 128;

  const unsigned short* qg = qb + ((size_t)(b * MM + m0)) * DMODEL + h * DHEAD;
  const unsigned short* kg = kb + ((size_t)b * NN) * DMODEL + h * DHEAD;
  const unsigned short* vg = vt + ((size_t)(b * NHEAD + h)) * (DHEAD * (size_t)NN);

  bf16x8 qf0, qf1;
  {
    const unsigned short* qrow = qg + (size_t)(wave * 16 + l15) * DMODEL;
    qf0 = *(const bf16x8*)(qrow + l4 * 8);
    qf1 = *(const bf16x8*)(qrow + 32 + l4 * 8);
  }

  bf16x8 ones;
  {
    const short one = (l15 == 0) ? (short)0x3f80 : (short)0;
#pragma unroll
    for (int j = 0; j < 8; ++j) ones[j] = one;
  }

  const int sr = tid >> 3;
  const int sc = (tid & 7) ^ (sr & 7);
  const unsigned short* kp = kg + (size_t)sr * DMODEL + (sc << 3);
  const unsigned short* vp = vg + (size_t)sr * NN + (sc << 3);
  const float* gp = lgb + (size_t)b * NN + lane;

  auto stage = [&](int buf) {
    if (wave == 0)
      __builtin_amdgcn_global_load_lds((const AS1 void*)gp, (AS3 void*)(&Gs[buf][lane]), 4, 0, 0);
    __builtin_amdgcn_global_load_lds((const AS1 void*)kp, (AS3 void*)(&Ks[buf][tid * 8]), 16, 0, 0);
    __builtin_amdgcn_global_load_lds((const AS1 void*)vp, (AS3 void*)(&Vs[buf][tid * 8]), 16, 0, 0);
    kp += 64 * DMODEL; vp += 64; gp += 64;
  };

  stage(0);

  f32x4 ovec[5] = {};
  float mrow = -1e30f;
  unsigned short* Pw = &Ps[wave][0];
  const int pbase = l15 * 128;
  const int s7 = l15 & 7;

  for (int nt = 0; nt < NN / 64; ++nt) {
    const int cur = nt & 1;
    asm volatile("s_waitcnt vmcnt(0)" ::: "memory");
    __builtin_amdgcn_sched_barrier(0);
    __builtin_amdgcn_s_barrier();
    __builtin_amdgcn_sched_barrier(0);
    if (nt < NN / 64 - 1) stage(cur ^ 1);

    f32x4 s[4];
    __builtin_amdgcn_s_setprio(1);
#pragma unroll
    for (int ni = 0; ni < 4; ++ni) {
      const int r = ni * 16 + l15;
      const int c0 = l4 ^ (r & 7);
      bf16x8 kf0 = *(const bf16x8*)&Ks[cur][r * 64 + (c0 << 3)];
      bf16x8 kf1 = *(const bf16x8*)&Ks[cur][r * 64 + ((c0 ^ 4) << 3)];
      f32x4 z = {};
      z = __builtin_amdgcn_mfma_f32_16x16x32_bf16(kf0, qf0, z, 0, 0, 0);
      s[ni] = __builtin_amdgcn_mfma_f32_16x16x32_bf16(kf1, qf1, z, 0, 0, 0);
    }
    __builtin_amdgcn_s_setprio(0);

    float tmax = -1e30f;
#pragma unroll
    for (int ni = 0; ni < 4; ++ni) {
      const float4 g = *(const float4*)&Gs[cur][ni * 16 + l4 * 4];
      s[ni][0] = fmaf(g.x, LOG2E, s[ni][0]);
      s[ni][1] = fmaf(g.y, LOG2E, s[ni][1]);
      s[ni][2] = fmaf(g.z, LOG2E, s[ni][2]);
      s[ni][3] = fmaf(g.w, LOG2E, s[ni][3]);
      tmax = fmaxf(tmax, fmaxf(fmaxf(s[ni][0], s[ni][1]), fmaxf(s[ni][2], s[ni][3])));
    }
    tmax = fmaxf(tmax, __shfl_xor(tmax, 16));
    tmax = fmaxf(tmax, __shfl_xor(tmax, 32));

    if (!__all(tmax <= mrow)) {
      const float mnew  = fmaxf(mrow, tmax);
      const float alpha = __builtin_amdgcn_exp2f(mrow - mnew);
      mrow = mnew;
      const int abase = l4 << 2;
#pragma unroll
      for (int i = 0; i < 4; ++i) {
        const float ai = __shfl(alpha, abase + i);
        ovec[0][i] *= ai; ovec[1][i] *= ai; ovec[2][i] *= ai;
        ovec[3][i] *= ai; ovec[4][i] *= ai;
      }
    }

#pragma unroll
    for (int ni = 0; ni < 4; ++ni) {
      union { unsigned short us[4]; uint2 u; } pk;
#pragma unroll
      for (int i = 0; i < 4; ++i)
        pk.us[i] = __builtin_bit_cast(unsigned short,
                     __float2bfloat16(__builtin_amdgcn_exp2f(s[ni][i] - mrow)));
      *(uint2*)((char*)Pw + pbase + (((ni * 4 + l4) ^ (s7 << 1)) << 3)) = pk.u;
    }
    asm volatile("s_waitcnt lgkmcnt(0)" ::: "memory");
    __builtin_amdgcn_sched_barrier(0);

    __builtin_amdgcn_s_setprio(1);
#pragma unroll
    for (int ks2 = 0; ks2 < 2; ++ks2) {
      const bf16x8 pf = *(const bf16x8*)((const char*)Pw + pbase + (((ks2 * 4 + l4) ^ s7) << 4));
#pragma unroll
      for (int di = 0; di < 4; ++di) {
        const int d = di * 16 + l15;
        const bf16x8 vf = *(const bf16x8*)&Vs[cur][d * 64 + (((ks2 * 4 + l4) ^ (d & 7)) << 3)];
        ovec[di] = __builtin_amdgcn_mfma_f32_16x16x32_bf16(pf, vf, ovec[di], 0, 0, 0);
      }
      ovec[4] = __builtin_amdgcn_mfma_f32_16x16x32_bf16(pf, ones, ovec[4], 0, 0, 0);
    }
    __builtin_amdgcn_s_setprio(0);
  }

  const int lsrc = lane & 48;
  float linv[4];
#pragma unroll
  for (int i = 0; i < 4; ++i)
    linv[i] = 1.0f / __shfl(ovec[4][i], lsrc);
#pragma unroll
  for (int di = 0; di < 4; ++di)
#pragma unroll
    for (int i = 0; i < 4; ++i) {
      const int row = m0 + wave * 16 + l4 * 4 + i;
      const int col = h * DHEAD + di * 16 + l15;
      attn[((size_t)(b * MM + row)) * DMODEL + col] =
        __builtin_bit_cast(unsigned short, __float2bfloat16(ovec[di][i] * linv[i]));
    }
}

// ---------------------------------------------------------------- LayerNorm
__global__ __launch_bounds__(256)
void ln_kernel(const float* __restrict__ x, const float* __restrict__ gamma,
               const float* __restrict__ beta, float* __restrict__ out)
{
  __shared__ float sh1[4], sh2[4];
  const int t = threadIdx.x;
  const size_t row = blockIdx.x;
  const float4 v = ((const float4*)(x + row * DMODEL))[t];

  float s = v.x + v.y + v.z + v.w;
#pragma unroll
  for (int m = 1; m < 64; m <<= 1) s += __shfl_xor(s, m);
  if ((t & 63) == 0) sh1[t >> 6] = s;
  __syncthreads();
  const float mu = (sh1[0] + sh1[1] + sh1[2] + sh1[3]) * (1.0f / DMODEL);

  const float dx = v.x - mu, dy = v.y - mu, dz = v.z - mu, dw = v.w - mu;
  float q = dx * dx + dy * dy + dz * dz + dw * dw;
#pragma unroll
  for (int m = 1; m < 64; m <<= 1) q += __shfl_xor(q, m);
  if ((t & 63) == 0) sh2[t >> 6] = q;
  __syncthreads();
  const float var = (sh2[0] + sh2[1] + sh2[2] + sh2[3]) * (1.0f / DMODEL);
  const float rstd = rsqrtf(var + 1e-5f);

  const float4 g  = ((const float4*)gamma)[t];
  const float4 be = ((const float4*)beta)[t];
  float4 o;
  o.x = dx * rstd * g.x + be.x;
  o.y = dy * rstd * g.y + be.y;
  o.z = dz * rstd * g.z + be.z;
  o.w = dw * rstd * g.w + be.w;
  ((float4*)(out + row * DMODEL))[t] = o;
}

// ---------------------------------------------------------------- launch
extern "C" void kernel_launch(void* const* d_in, const int* in_sizes, int n_in,
                              void* d_out, int out_size, void* d_ws, size_t ws_size,
                              hipStream_t stream)
{
  const float* Qf    = (const float*)d_in[0];
  const float* KVf   = (const float*)d_in[1];
  const float* lgb   = (const float*)d_in[2];
  const float* Wq    = (const float*)d_in[3];
  const float* bq    = (const float*)d_in[4];
  const float* Wk    = (const float*)d_in[5];
  const float* bk    = (const float*)d_in[6];
  const float* Wv    = (const float*)d_in[7];
  const float* bv    = (const float*)d_in[8];
  const float* Wo    = (const float*)d_in[9];
  const float* bo    = (const float*)d_in[10];
  const float* gamma = (const float*)d_in[11];
  const float* beta  = (const float*)d_in[12];
  float* out = (float*)d_out;

  char* ws = (char*)d_ws;
  unsigned short* Qbf   = (unsigned short*)(ws + 0);
  unsigned short* attnb = Qbf;
  unsigned short* KVbf  = (unsigned short*)(ws + 8388608);
  float*          xbuf  = (float*)(ws + 8388608);
  unsigned short* Wqb = (unsigned short*)(ws + 25165824);
  unsigned short* Wkb = (unsigned short*)(ws + 27262976);
  unsigned short* Wvb = (unsigned short*)(ws + 29360128);
  unsigned short* Wob = (unsigned short*)(ws + 31457280);
  unsigned short* qbuf  = (unsigned short*)(ws + 33554432);
  unsigned short* kbuf  = (unsigned short*)(ws + 41943040);
  unsigned short* vtbuf = (unsigned short*)(ws + 58720256);

  cast_all<<<16384, dim3(256), 0, stream>>>(Qf, KVf, Wq, Wk, Wv, Wo,
                                            Qbf, KVbf, Wqb, Wkb, Wvb, Wob);

  qkv_gemm<<<1280, dim3(256), 0, stream>>>(Qbf, KVbf, Wqb, Wkb, Wvb,
                                           bq, bk, bv, qbuf, kbuf, vtbuf);

  attn_kernel<<<512, dim3(512), 0, stream>>>(qbuf, kbuf, vtbuf, lgb, attnb);

  gemm_o<<<512, dim3(256), 0, stream>>>(attnb, Wob, bo, Qf, xbuf);

  ln_kernel<<<4096, dim3(256), 0, stream>>>(xbuf, gamma, beta, out);
}